// Round 1
// baseline (2473.104 us; speedup 1.0000x reference)
//
#include <hip/hip_runtime.h>
#include <math.h>

// Problem constants (match reference setup_inputs)
constexpr int N_  = 50000;
constexpr int E_  = 500000;
constexpr int FIN = 128;   // input feature dim
constexpr int HID_ = 64;
constexpr int H_  = 2;     // heads

#define DINL __device__ __forceinline__

DINL float gelu_f(float x) { return 0.5f * x * (1.f + erff(x * 0.70710678118654752f)); }
DINL float sigmoid_f(float x) { return 1.f / (1.f + expf(-x)); }

// float atomic max via monotone int/uint encodings
DINL void atomicMaxF(float* addr, float val) {
  if (val >= 0.f) atomicMax((int*)addr, __float_as_int(val));
  else            atomicMin((unsigned int*)addr, __float_as_uint(val));
}

// ---------------- degree ----------------
__global__ void deg_kernel(const int* __restrict__ dst, float* __restrict__ deg) {
  int t = blockIdx.x * 256 + threadIdx.x;
  if (t < E_) atomicAdd(&deg[dst[t]], 1.f);
}

__global__ void fill_neginf(float* __restrict__ p, int n) {
  int t = blockIdx.x * 256 + threadIdx.x;
  if (t < n) p[t] = -INFINITY;
}

// ---------------- feature mask: out = feat * sigmoid(feat@W + b) ----------------
// K=C=128. 8 rows/block, 256 threads.
__global__ __launch_bounds__(256) void mask_kernel(const float* __restrict__ feat,
    const float* __restrict__ W, const float* __restrict__ b, float* __restrict__ out) {
  __shared__ float a[8 * 128];
  const int tid = threadIdx.x;
  const long base = (long)blockIdx.x * 8 * 128;
  ((float4*)a)[tid] = ((const float4*)(feat + base))[tid];   // 256 float4 = 1024 floats
  __syncthreads();
  const int c = tid & 127;
  const int rs = tid >> 7;                 // 0..1, rows rs + 2j
  float acc[4] = {0.f, 0.f, 0.f, 0.f};
  for (int k = 0; k < 128; ++k) {
    float w = W[k * 128 + c];
#pragma unroll
    for (int j = 0; j < 4; ++j) acc[j] += a[(rs + 2 * j) * 128 + k] * w;
  }
  float bc = b[c];
#pragma unroll
  for (int j = 0; j < 4; ++j) {
    int r = rs + 2 * j;
    float s = acc[j] + bc;
    out[base + r * 128 + c] = a[r * 128 + c] * sigmoid_f(s);
  }
}

// ---------------- dual GEMM (no bias): O1 = A@W1, O2 = A@W2, C=128 ----------------
template <int K>
__global__ __launch_bounds__(256) void gemm_dual(const float* __restrict__ A,
    const float* __restrict__ W1, const float* __restrict__ W2,
    float* __restrict__ O1, float* __restrict__ O2) {
  __shared__ float a[8 * K];
  const int tid = threadIdx.x;
  const long base = (long)blockIdx.x * 8 * K;
  constexpr int NV = 8 * K / 4;
  for (int i = tid; i < NV; i += 256) ((float4*)a)[i] = ((const float4*)(A + base))[i];
  __syncthreads();
  const int c = tid & 127;
  const int rs = tid >> 7;                 // rows rs + 2j, j<4
  float acc1[4] = {0.f, 0.f, 0.f, 0.f};
  float acc2[4] = {0.f, 0.f, 0.f, 0.f};
  for (int k = 0; k < K; ++k) {
    float w1 = W1[k * 128 + c];
    float w2 = W2[k * 128 + c];
#pragma unroll
    for (int j = 0; j < 4; ++j) {
      float av = a[(rs + 2 * j) * K + k];
      acc1[j] += av * w1;
      acc2[j] += av * w2;
    }
  }
#pragma unroll
  for (int j = 0; j < 4; ++j) {
    long orow = (long)blockIdx.x * 8 + rs + 2 * j;
    O1[orow * 128 + c] = acc1[j];
    O2[orow * 128 + c] = acc2[j];
  }
}

// ---------------- SAGE linear: out = epi(h@Wself + (agg/deg)@Wneigh + b) ----------------
template <int K, bool DROP>
__global__ __launch_bounds__(256) void sage_linear(const float* __restrict__ h,
    const float* __restrict__ agg, const float* __restrict__ deg,
    const float* __restrict__ Wself, const float* __restrict__ Wneigh,
    const float* __restrict__ bias, const float* __restrict__ drop,
    float* __restrict__ out) {
  __shared__ float a[8 * K];
  __shared__ float an[8 * K];
  const int tid = threadIdx.x;
  const int row0 = blockIdx.x * 8;
  constexpr int NV = 8 * K / 4;
  for (int i = tid; i < NV; i += 256) {
    ((float4*)a)[i] = ((const float4*)(h + (long)row0 * K))[i];
    float4 v = ((const float4*)(agg + (long)row0 * K))[i];
    int r = i / (K / 4);
    float inv = 1.f / fmaxf(deg[row0 + r], 1.f);
    v.x *= inv; v.y *= inv; v.z *= inv; v.w *= inv;
    ((float4*)an)[i] = v;
  }
  __syncthreads();
  const int c = tid & 63;
  const int rs = tid >> 6;                 // 0..3, rows rs + 4j, j<2
  float acc[2] = {0.f, 0.f};
  for (int k = 0; k < K; ++k) {
    float wsv = Wself[k * 64 + c];
    float wnv = Wneigh[k * 64 + c];
#pragma unroll
    for (int j = 0; j < 2; ++j) {
      int r = rs + 4 * j;
      acc[j] += a[r * K + k] * wsv + an[r * K + k] * wnv;
    }
  }
  float bc = bias[c];
#pragma unroll
  for (int j = 0; j < 2; ++j) {
    long r = row0 + rs + 4 * j;
    float x = acc[j] + bc;
    float g = gelu_f(x);
    if constexpr (DROP) g *= drop[r * 64 + c];
    out[r * 64 + c] = g;
  }
}

// ---------------- scatter add: agg[dst] += h[src], K floats/edge ----------------
template <int K>
__global__ void scatter_add(const float* __restrict__ h, const int* __restrict__ src,
                            const int* __restrict__ dst, float* __restrict__ agg) {
  constexpr int VQ = K / 4;
  int t = blockIdx.x * 256 + threadIdx.x;
  if (t >= E_ * VQ) return;
  int e = t / VQ, q = t - e * VQ;
  int s = src[e], d = dst[e];
  float4 v = *(const float4*)(h + (long)s * K + q * 4);
  float* o = agg + (long)d * K + q * 4;
  atomicAdd(o + 0, v.x); atomicAdd(o + 1, v.y);
  atomicAdd(o + 2, v.z); atomicAdd(o + 3, v.w);
}

// ---------------- GATv2 edge pass 1: logits + segment max ----------------
// one 64-lane wave per edge
__global__ __launch_bounds__(256) void gat_edge_logits(const float* __restrict__ fs,
    const float* __restrict__ fd, const int* __restrict__ src, const int* __restrict__ dst,
    const float* __restrict__ attn, float* __restrict__ logits, float* __restrict__ m) {
  int w = (blockIdx.x * 256 + threadIdx.x) >> 6;
  int lane = threadIdx.x & 63;
  if (w >= E_) return;
  int s = src[w], d = dst[w];
#pragma unroll
  for (int h = 0; h < H_; ++h) {
    float x = fs[(long)s * 128 + h * 64 + lane] + fd[(long)d * 128 + h * 64 + lane];
    x = x > 0.f ? x : 0.2f * x;
    float p = x * attn[h * 64 + lane];
#pragma unroll
    for (int o = 32; o; o >>= 1) p += __shfl_xor(p, o);
    if (lane == 0) {
      logits[(long)w * 2 + h] = p;
      atomicMaxF(&m[(long)d * 2 + h], p);
    }
  }
}

// ---------------- GATv2 edge pass 2: exp, denom sum, weighted scatter ----------------
__global__ __launch_bounds__(256) void gat_edge_scatter(const float* __restrict__ fs,
    const int* __restrict__ src, const int* __restrict__ dst,
    const float* __restrict__ logits, const float* __restrict__ m,
    float* __restrict__ denom, float* __restrict__ outbuf) {
  int w = (blockIdx.x * 256 + threadIdx.x) >> 6;
  int lane = threadIdx.x & 63;
  if (w >= E_) return;
  int s = src[w], d = dst[w];
#pragma unroll
  for (int h = 0; h < H_; ++h) {
    float ex = expf(logits[(long)w * 2 + h] - m[(long)d * 2 + h]);
    atomicAdd(&outbuf[(long)d * 128 + h * 64 + lane], ex * fs[(long)s * 128 + h * 64 + lane]);
    if (lane == 0) atomicAdd(&denom[(long)d * 2 + h], ex);
  }
}

// ---------------- GAT node epilogue layer1: mean-head gelu, dropout ----------------
__global__ void gat_node1(const float* __restrict__ go, const float* __restrict__ dn,
                          const float* __restrict__ bias, const float* __restrict__ drop,
                          float* __restrict__ out) {
  int t = blockIdx.x * 256 + threadIdx.x;
  if (t >= N_ * 64) return;
  int r = t >> 6, c = t & 63;
  float v = 0.f;
#pragma unroll
  for (int h = 0; h < H_; ++h) {
    float d = dn[r * 2 + h];
    float x = bias[h * 64 + c];
    if (d > 0.f) x += go[(long)r * 128 + h * 64 + c] / d;
    v += gelu_f(x);
  }
  out[t] = 0.5f * v * drop[t];
}

// ---------------- GAT node epilogue layer2: mean-head gelu, l2norm ----------------
__global__ __launch_bounds__(256) void gat_node2(const float* __restrict__ go,
    const float* __restrict__ dn, const float* __restrict__ bias, float* __restrict__ out) {
  int tid = threadIdx.x;
  int r = blockIdx.x * 4 + (tid >> 6);
  int c = tid & 63;
  float v = 0.f;
#pragma unroll
  for (int h = 0; h < H_; ++h) {
    float d = dn[r * 2 + h];
    float x = bias[h * 64 + c];
    if (d > 0.f) x += go[(long)r * 128 + h * 64 + c] / d;
    v += gelu_f(x);
  }
  v *= 0.5f;
  float ss = v * v;
#pragma unroll
  for (int o = 32; o; o >>= 1) ss += __shfl_xor(ss, o);
  float sc = 1.f / fmaxf(sqrtf(ss), 1e-12f);
  out[(long)r * 64 + c] = v * sc;
}

// ---------------- final topology: concat([h2, feat])@W3 + b3, leaky, l2norm ----------------
__global__ __launch_bounds__(256) void final_t(const float* __restrict__ h2,
    const float* __restrict__ feat, const float* __restrict__ W3,
    const float* __restrict__ b3, float* __restrict__ out) {
  __shared__ float a[8 * 64];
  __shared__ float f[8 * 128];
  const int tid = threadIdx.x;
  const int row0 = blockIdx.x * 8;
  for (int i = tid; i < 128; i += 256)
    ((float4*)a)[i] = ((const float4*)(h2 + (long)row0 * 64))[i];
  ((float4*)f)[tid] = ((const float4*)(feat + (long)row0 * 128))[tid];
  __syncthreads();
  const int c = tid & 63;
  const int rs = tid >> 6;                // rows rs, rs+4
  float acc[2] = {0.f, 0.f};
  for (int k = 0; k < 64; ++k) {
    float w = W3[k * 64 + c];
    acc[0] += a[rs * 64 + k] * w;
    acc[1] += a[(rs + 4) * 64 + k] * w;
  }
  for (int k = 0; k < 128; ++k) {
    float w = W3[(64 + k) * 64 + c];
    acc[0] += f[rs * 128 + k] * w;
    acc[1] += f[(rs + 4) * 128 + k] * w;
  }
  float bc = b3[c];
#pragma unroll
  for (int j = 0; j < 2; ++j) {
    float x = acc[j] + bc;
    x = x > 0.f ? x : 0.01f * x;
    float ss = x * x;
#pragma unroll
    for (int o = 32; o; o >>= 1) ss += __shfl_xor(ss, o);
    float sc = 1.f / fmaxf(sqrtf(ss), 1e-12f);
    out[(long)(row0 + rs + 4 * j) * 64 + c] = x * sc;
  }
}

extern "C" void kernel_launch(void* const* d_in, const int* in_sizes, int n_in,
                              void* d_out, int out_size, void* d_ws, size_t ws_size,
                              hipStream_t stream) {
  const float* feat = (const float*)d_in[0];
  const int*   esrc = (const int*)d_in[1];
  const int*   edst = (const int*)d_in[2];
  const float* Wmt = (const float*)d_in[3],  *bmt = (const float*)d_in[4];
  const float* Wms = (const float*)d_in[5],  *bms = (const float*)d_in[6];
  const float* W1s = (const float*)d_in[7],  *W1n = (const float*)d_in[8],  *b1 = (const float*)d_in[9];
  const float* W2s = (const float*)d_in[10], *W2n = (const float*)d_in[11], *b2 = (const float*)d_in[12];
  const float* g1Ws = (const float*)d_in[13], *g1Wd = (const float*)d_in[14];
  const float* g1a  = (const float*)d_in[15], *g1b  = (const float*)d_in[16];
  const float* g2Ws = (const float*)d_in[17], *g2Wd = (const float*)d_in[18];
  const float* g2a  = (const float*)d_in[19], *g2b  = (const float*)d_in[20];
  const float* W3  = (const float*)d_in[21], *b3 = (const float*)d_in[22];
  const float* dropt = (const float*)d_in[23], *drops = (const float*)d_in[24];

  float* out_t = (float*)d_out;
  float* out_s = out_t + (long)N_ * 64;

  // workspace layout (floats); total 30.05M floats = 120.2 MB
  float* ws = (float*)d_ws;
  float* A   = ws;              // N*128   h_t0 / h_s0 / gat_out
  float* Bf  = ws +  6400000;   // N*128   sage agg / fs
  float* Cf  = ws + 12800000;   // N*128   fd
  float* Df  = ws + 19200000;   // N*64    h1 / h_s1
  float* Ef  = ws + 22400000;   // N*64    sage2 agg
  float* Ff  = ws + 25600000;   // N*64    h2
  float* deg = ws + 28800000;   // N
  float* lg  = ws + 28850000;   // E*2     logits
  float* mx  = ws + 29850000;   // N*2     segment max
  float* dn  = ws + 29950000;   // N*2     softmax denom

  // degrees (shared by both SAGE layers)
  hipMemsetAsync(deg, 0, N_ * sizeof(float), stream);
  deg_kernel<<<(E_ + 255) / 256, 256, 0, stream>>>(edst, deg);

  // ---- topology branch ----
  mask_kernel<<<N_ / 8, 256, 0, stream>>>(feat, Wmt, bmt, A);                 // h_t0
  hipMemsetAsync(Bf, 0, (size_t)N_ * 128 * sizeof(float), stream);
  scatter_add<128><<<E_ * 32 / 256, 256, 0, stream>>>(A, esrc, edst, Bf);
  sage_linear<128, true><<<N_ / 8, 256, 0, stream>>>(A, Bf, deg, W1s, W1n, b1, dropt, Df); // h1
  hipMemsetAsync(Ef, 0, (size_t)N_ * 64 * sizeof(float), stream);
  scatter_add<64><<<E_ * 16 / 256, 256, 0, stream>>>(Df, esrc, edst, Ef);
  sage_linear<64, false><<<N_ / 8, 256, 0, stream>>>(Df, Ef, deg, W2s, W2n, b2, nullptr, Ff); // h2
  final_t<<<N_ / 8, 256, 0, stream>>>(Ff, feat, W3, b3, out_t);

  // ---- semantic branch ----
  mask_kernel<<<N_ / 8, 256, 0, stream>>>(feat, Wms, bms, A);                 // h_s0
  gemm_dual<128><<<N_ / 8, 256, 0, stream>>>(A, g1Ws, g1Wd, Bf, Cf);          // fs, fd
  fill_neginf<<<(N_ * 2 + 255) / 256, 256, 0, stream>>>(mx, N_ * 2);
  gat_edge_logits<<<E_ * 64 / 256, 256, 0, stream>>>(Bf, Cf, esrc, edst, g1a, lg, mx);
  hipMemsetAsync(dn, 0, N_ * 2 * sizeof(float), stream);
  hipMemsetAsync(A, 0, (size_t)N_ * 128 * sizeof(float), stream);             // gat_out
  gat_edge_scatter<<<E_ * 64 / 256, 256, 0, stream>>>(Bf, esrc, edst, lg, mx, dn, A);
  gat_node1<<<N_ * 64 / 256, 256, 0, stream>>>(A, dn, g1b, drops, Df);        // h_s1

  gemm_dual<64><<<N_ / 8, 256, 0, stream>>>(Df, g2Ws, g2Wd, Bf, Cf);          // fs2, fd2
  fill_neginf<<<(N_ * 2 + 255) / 256, 256, 0, stream>>>(mx, N_ * 2);
  gat_edge_logits<<<E_ * 64 / 256, 256, 0, stream>>>(Bf, Cf, esrc, edst, g2a, lg, mx);
  hipMemsetAsync(dn, 0, N_ * 2 * sizeof(float), stream);
  hipMemsetAsync(A, 0, (size_t)N_ * 128 * sizeof(float), stream);
  gat_edge_scatter<<<E_ * 64 / 256, 256, 0, stream>>>(Bf, esrc, edst, lg, mx, dn, A);
  gat_node2<<<N_ / 4, 256, 0, stream>>>(A, dn, g2b, out_s);
}

// Round 2
// 764.190 us; speedup vs baseline: 3.2362x; 3.2362x over previous
//
#include <hip/hip_runtime.h>
#include <math.h>

constexpr int N_  = 50000;
constexpr int E_  = 500000;
constexpr int H_  = 2;

#define DINL __device__ __forceinline__

DINL float gelu_f(float x) { return 0.5f * x * (1.f + erff(x * 0.70710678118654752f)); }
DINL float sigmoid_f(float x) { return 1.f / (1.f + expf(-x)); }

// ---------------- CSR build ----------------
__global__ void deg_int_kernel(const int* __restrict__ dst, int* __restrict__ deg) {
  int t = blockIdx.x * 256 + threadIdx.x;
  if (t < E_) atomicAdd(&deg[dst[t]], 1);
}

// single-block exclusive scan over n ints (n ~ 50000), 1024 threads
__global__ __launch_bounds__(1024) void scan_kernel(const int* __restrict__ deg,
                                                    int* __restrict__ rowptr, int n) {
  __shared__ int sums[16];
  __shared__ int s_carry;
  const int tid = threadIdx.x, lane = tid & 63, wid = tid >> 6;
  if (tid == 0) s_carry = 0;
  __syncthreads();
  for (int base = 0; base < n; base += 1024) {
    int i = base + tid;
    int v = (i < n) ? deg[i] : 0;
    int x = v;
#pragma unroll
    for (int o = 1; o < 64; o <<= 1) { int y = __shfl_up(x, o); if (lane >= o) x += y; }
    if (lane == 63) sums[wid] = x;
    __syncthreads();
    if (wid == 0) {
      int s = (lane < 16) ? sums[lane] : 0;
#pragma unroll
      for (int o = 1; o < 16; o <<= 1) { int y = __shfl_up(s, o); if (lane >= o) s += y; }
      if (lane < 16) sums[lane] = s;
    }
    __syncthreads();
    int waveoff = wid ? sums[wid - 1] : 0;
    int incl = x + waveoff + s_carry;
    if (i < n) rowptr[i] = incl - v;     // exclusive
    __syncthreads();
    if (tid == 1023) s_carry = incl;
    __syncthreads();
  }
  if (tid == 0) rowptr[n] = s_carry;
}

__global__ void csr_fill(const int* __restrict__ src, const int* __restrict__ dst,
                         const int* __restrict__ rowptr, int* __restrict__ cursor,
                         int* __restrict__ colsrc) {
  int e = blockIdx.x * 256 + threadIdx.x;
  if (e >= E_) return;
  int d = dst[e];
  int pos = rowptr[d] + atomicAdd(&cursor[d], 1);
  colsrc[pos] = src[e];
}

// ---------------- feature mask: out = feat * sigmoid(feat@W + b) ----------------
__global__ __launch_bounds__(256) void mask_kernel(const float* __restrict__ feat,
    const float* __restrict__ W, const float* __restrict__ b, float* __restrict__ out) {
  __shared__ float a[8 * 128];
  const int tid = threadIdx.x;
  const long base = (long)blockIdx.x * 8 * 128;
  ((float4*)a)[tid] = ((const float4*)(feat + base))[tid];
  __syncthreads();
  const int c = tid & 127;
  const int rs = tid >> 7;
  float acc[4] = {0.f, 0.f, 0.f, 0.f};
  for (int k = 0; k < 128; ++k) {
    float w = W[k * 128 + c];
#pragma unroll
    for (int j = 0; j < 4; ++j) acc[j] += a[(rs + 2 * j) * 128 + k] * w;
  }
  float bc = b[c];
#pragma unroll
  for (int j = 0; j < 4; ++j) {
    int r = rs + 2 * j;
    float s = acc[j] + bc;
    out[base + r * 128 + c] = a[r * 128 + c] * sigmoid_f(s);
  }
}

// ---------------- dual GEMM: O1 = A@W1, O2 = A@W2 (C=128) ----------------
template <int K>
__global__ __launch_bounds__(256) void gemm_dual(const float* __restrict__ A,
    const float* __restrict__ W1, const float* __restrict__ W2,
    float* __restrict__ O1, float* __restrict__ O2) {
  __shared__ float a[8 * K];
  const int tid = threadIdx.x;
  const long base = (long)blockIdx.x * 8 * K;
  constexpr int NV = 8 * K / 4;
  for (int i = tid; i < NV; i += 256) ((float4*)a)[i] = ((const float4*)(A + base))[i];
  __syncthreads();
  const int c = tid & 127;
  const int rs = tid >> 7;
  float acc1[4] = {0.f, 0.f, 0.f, 0.f};
  float acc2[4] = {0.f, 0.f, 0.f, 0.f};
  for (int k = 0; k < K; ++k) {
    float w1 = W1[k * 128 + c];
    float w2 = W2[k * 128 + c];
#pragma unroll
    for (int j = 0; j < 4; ++j) {
      float av = a[(rs + 2 * j) * K + k];
      acc1[j] += av * w1;
      acc2[j] += av * w2;
    }
  }
#pragma unroll
  for (int j = 0; j < 4; ++j) {
    long orow = (long)blockIdx.x * 8 + rs + 2 * j;
    O1[orow * 128 + c] = acc1[j];
    O2[orow * 128 + c] = acc2[j];
  }
}

// ---------------- SAGE gather: out[n] = sum_{e in CSR(n)} h[src_e] ----------------
template <int K>
__global__ __launch_bounds__(256) void gather_sum(const float* __restrict__ h,
    const int* __restrict__ rowptr, const int* __restrict__ colsrc,
    float* __restrict__ out) {
  int node = blockIdx.x * 4 + (threadIdx.x >> 6);
  int lane = threadIdx.x & 63;
  if (node >= N_) return;
  int beg = rowptr[node], end = rowptr[node + 1];
  if constexpr (K == 128) {
    float a0 = 0.f, a1 = 0.f;
    for (int j = beg; j < end; ++j) {
      int s = colsrc[j];
      a0 += h[(long)s * 128 + lane];
      a1 += h[(long)s * 128 + 64 + lane];
    }
    out[(long)node * 128 + lane] = a0;
    out[(long)node * 128 + 64 + lane] = a1;
  } else {
    float a0 = 0.f;
    for (int j = beg; j < end; ++j) a0 += h[(long)colsrc[j] * 64 + lane];
    out[(long)node * 64 + lane] = a0;
  }
}

// ---------------- SAGE linear: out = epi(h@Wself + (agg/deg)@Wneigh + b) ----------------
template <int K, bool DROP>
__global__ __launch_bounds__(256) void sage_linear(const float* __restrict__ h,
    const float* __restrict__ agg, const int* __restrict__ degi,
    const float* __restrict__ Wself, const float* __restrict__ Wneigh,
    const float* __restrict__ bias, const float* __restrict__ drop,
    float* __restrict__ out) {
  __shared__ float a[8 * K];
  __shared__ float an[8 * K];
  const int tid = threadIdx.x;
  const int row0 = blockIdx.x * 8;
  constexpr int NV = 8 * K / 4;
  for (int i = tid; i < NV; i += 256) {
    ((float4*)a)[i] = ((const float4*)(h + (long)row0 * K))[i];
    float4 v = ((const float4*)(agg + (long)row0 * K))[i];
    int r = i / (K / 4);
    float inv = 1.f / fmaxf((float)degi[row0 + r], 1.f);
    v.x *= inv; v.y *= inv; v.z *= inv; v.w *= inv;
    ((float4*)an)[i] = v;
  }
  __syncthreads();
  const int c = tid & 63;
  const int rs = tid >> 6;
  float acc[2] = {0.f, 0.f};
  for (int k = 0; k < K; ++k) {
    float wsv = Wself[k * 64 + c];
    float wnv = Wneigh[k * 64 + c];
#pragma unroll
    for (int j = 0; j < 2; ++j) {
      int r = rs + 4 * j;
      acc[j] += a[r * K + k] * wsv + an[r * K + k] * wnv;
    }
  }
  float bc = bias[c];
#pragma unroll
  for (int j = 0; j < 2; ++j) {
    long r = row0 + rs + 4 * j;
    float x = acc[j] + bc;
    float g = gelu_f(x);
    if constexpr (DROP) g *= drop[r * 64 + c];
    out[r * 64 + c] = g;
  }
}

// ---------------- fused GATv2 layer: online softmax + weighted gather + epilogue ----------------
// one wave per node; lane owns column `lane` of both heads
template <bool LAYER1>
__global__ __launch_bounds__(256) void gat_fused(const float* __restrict__ fs,
    const float* __restrict__ fd, const int* __restrict__ rowptr,
    const int* __restrict__ colsrc, const float* __restrict__ attn,
    const float* __restrict__ bias, const float* __restrict__ drop,
    float* __restrict__ out) {
  int node = blockIdx.x * 4 + (threadIdx.x >> 6);
  int lane = threadIdx.x & 63;
  if (node >= N_) return;
  const float a0 = attn[lane], a1 = attn[64 + lane];
  const float fd0 = fd[(long)node * 128 + lane];
  const float fd1 = fd[(long)node * 128 + 64 + lane];
  float m0 = -INFINITY, m1 = -INFINITY;
  float d0 = 0.f, d1 = 0.f, acc0 = 0.f, acc1 = 0.f;
  const int beg = rowptr[node], end = rowptr[node + 1];
  for (int j = beg; j < end; ++j) {
    int s = colsrc[j];
    float f0 = fs[(long)s * 128 + lane];
    float f1 = fs[(long)s * 128 + 64 + lane];
    float x0 = f0 + fd0; x0 = x0 > 0.f ? x0 : 0.2f * x0;
    float x1 = f1 + fd1; x1 = x1 > 0.f ? x1 : 0.2f * x1;
    float p0 = x0 * a0, p1 = x1 * a1;
#pragma unroll
    for (int o = 32; o; o >>= 1) { p0 += __shfl_xor(p0, o); p1 += __shfl_xor(p1, o); }
    float nm0 = fmaxf(m0, p0), nm1 = fmaxf(m1, p1);
    float s0 = expf(m0 - nm0), s1 = expf(m1 - nm1);   // exp(-inf)=0 on first edge
    float e0 = expf(p0 - nm0), e1 = expf(p1 - nm1);
    d0 = d0 * s0 + e0;       d1 = d1 * s1 + e1;
    acc0 = acc0 * s0 + e0 * f0;
    acc1 = acc1 * s1 + e1 * f1;
    m0 = nm0; m1 = nm1;
  }
  float o0 = bias[lane]      + (d0 > 0.f ? acc0 / d0 : 0.f);
  float o1 = bias[64 + lane] + (d1 > 0.f ? acc1 / d1 : 0.f);
  float v = 0.5f * (gelu_f(o0) + gelu_f(o1));
  if constexpr (LAYER1) {
    out[(long)node * 64 + lane] = v * drop[(long)node * 64 + lane];
  } else {
    float ss = v * v;
#pragma unroll
    for (int o = 32; o; o >>= 1) ss += __shfl_xor(ss, o);
    out[(long)node * 64 + lane] = v / fmaxf(sqrtf(ss), 1e-12f);
  }
}

// ---------------- final topology: concat([h2, feat])@W3 + b3, leaky, l2norm ----------------
__global__ __launch_bounds__(256) void final_t(const float* __restrict__ h2,
    const float* __restrict__ feat, const float* __restrict__ W3,
    const float* __restrict__ b3, float* __restrict__ out) {
  __shared__ float a[8 * 64];
  __shared__ float f[8 * 128];
  const int tid = threadIdx.x;
  const int row0 = blockIdx.x * 8;
  for (int i = tid; i < 128; i += 256)
    ((float4*)a)[i] = ((const float4*)(h2 + (long)row0 * 64))[i];
  ((float4*)f)[tid] = ((const float4*)(feat + (long)row0 * 128))[tid];
  __syncthreads();
  const int c = tid & 63;
  const int rs = tid >> 6;
  float acc[2] = {0.f, 0.f};
  for (int k = 0; k < 64; ++k) {
    float w = W3[k * 64 + c];
    acc[0] += a[rs * 64 + k] * w;
    acc[1] += a[(rs + 4) * 64 + k] * w;
  }
  for (int k = 0; k < 128; ++k) {
    float w = W3[(64 + k) * 64 + c];
    acc[0] += f[rs * 128 + k] * w;
    acc[1] += f[(rs + 4) * 128 + k] * w;
  }
  float bc = b3[c];
#pragma unroll
  for (int j = 0; j < 2; ++j) {
    float x = acc[j] + bc;
    x = x > 0.f ? x : 0.01f * x;
    float ss = x * x;
#pragma unroll
    for (int o = 32; o; o >>= 1) ss += __shfl_xor(ss, o);
    float sc = 1.f / fmaxf(sqrtf(ss), 1e-12f);
    out[(long)(row0 + rs + 4 * j) * 64 + c] = x * sc;
  }
}

extern "C" void kernel_launch(void* const* d_in, const int* in_sizes, int n_in,
                              void* d_out, int out_size, void* d_ws, size_t ws_size,
                              hipStream_t stream) {
  const float* feat = (const float*)d_in[0];
  const int*   esrc = (const int*)d_in[1];
  const int*   edst = (const int*)d_in[2];
  const float* Wmt = (const float*)d_in[3],  *bmt = (const float*)d_in[4];
  const float* Wms = (const float*)d_in[5],  *bms = (const float*)d_in[6];
  const float* W1s = (const float*)d_in[7],  *W1n = (const float*)d_in[8],  *b1 = (const float*)d_in[9];
  const float* W2s = (const float*)d_in[10], *W2n = (const float*)d_in[11], *b2 = (const float*)d_in[12];
  const float* g1Ws = (const float*)d_in[13], *g1Wd = (const float*)d_in[14];
  const float* g1a  = (const float*)d_in[15], *g1b  = (const float*)d_in[16];
  const float* g2Ws = (const float*)d_in[17], *g2Wd = (const float*)d_in[18];
  const float* g2a  = (const float*)d_in[19], *g2b  = (const float*)d_in[20];
  const float* W3  = (const float*)d_in[21], *b3 = (const float*)d_in[22];
  const float* dropt = (const float*)d_in[23], *drops = (const float*)d_in[24];

  float* out_t = (float*)d_out;
  float* out_s = out_t + (long)N_ * 64;

  // workspace layout
  float* ws = (float*)d_ws;
  float* A   = ws;              // N*128
  float* Bf  = ws +  6400000;   // N*128
  float* Cf  = ws + 12800000;   // N*128
  float* Df  = ws + 19200000;   // N*64
  float* Ef  = ws + 22400000;   // N*64
  float* Ff  = ws + 25600000;   // N*64
  int* degi   = (int*)(ws + 28800000);   // N
  int* rowptr = degi + N_;               // N+1
  int* cursor = rowptr + N_ + 1;         // N
  int* colsrc = cursor + N_;             // E

  // ---- CSR build (shared by SAGE + GAT layers) ----
  hipMemsetAsync(degi, 0, (2 * N_ + 1) * sizeof(int), stream);   // degi + rowptr head ok; cursor below
  hipMemsetAsync(cursor, 0, N_ * sizeof(int), stream);
  deg_int_kernel<<<(E_ + 255) / 256, 256, 0, stream>>>(edst, degi);
  scan_kernel<<<1, 1024, 0, stream>>>(degi, rowptr, N_);
  csr_fill<<<(E_ + 255) / 256, 256, 0, stream>>>(esrc, edst, rowptr, cursor, colsrc);

  // ---- topology branch (SAGE) ----
  mask_kernel<<<N_ / 8, 256, 0, stream>>>(feat, Wmt, bmt, A);                  // h_t0
  gather_sum<128><<<N_ / 4, 256, 0, stream>>>(A, rowptr, colsrc, Bf);
  sage_linear<128, true><<<N_ / 8, 256, 0, stream>>>(A, Bf, degi, W1s, W1n, b1, dropt, Df);
  gather_sum<64><<<N_ / 4, 256, 0, stream>>>(Df, rowptr, colsrc, Ef);
  sage_linear<64, false><<<N_ / 8, 256, 0, stream>>>(Df, Ef, degi, W2s, W2n, b2, nullptr, Ff);
  final_t<<<N_ / 8, 256, 0, stream>>>(Ff, feat, W3, b3, out_t);

  // ---- semantic branch (GATv2) ----
  mask_kernel<<<N_ / 8, 256, 0, stream>>>(feat, Wms, bms, A);                  // h_s0
  gemm_dual<128><<<N_ / 8, 256, 0, stream>>>(A, g1Ws, g1Wd, Bf, Cf);           // fs, fd
  gat_fused<true><<<N_ / 4, 256, 0, stream>>>(Bf, Cf, rowptr, colsrc, g1a, g1b, drops, Df);
  gemm_dual<64><<<N_ / 8, 256, 0, stream>>>(Df, g2Ws, g2Wd, Bf, Cf);           // fs2, fd2
  gat_fused<false><<<N_ / 4, 256, 0, stream>>>(Bf, Cf, rowptr, colsrc, g2a, g2b, nullptr, out_s);
}

// Round 3
// 509.250 us; speedup vs baseline: 4.8564x; 1.5006x over previous
//
#include <hip/hip_runtime.h>
#include <math.h>

constexpr int N_  = 50000;
constexpr int E_  = 500000;

typedef unsigned short u16;
typedef short short8 __attribute__((ext_vector_type(8)));
typedef __bf16 bf16x8 __attribute__((ext_vector_type(8)));
typedef float f32x4 __attribute__((ext_vector_type(4)));
typedef short short4v __attribute__((ext_vector_type(4)));

#define DINL __device__ __forceinline__

DINL float gelu_f(float x) { return 0.5f * x * (1.f + erff(x * 0.70710678118654752f)); }
DINL float sigmoid_f(float x) { return 1.f / (1.f + expf(-x)); }
DINL u16 f2b(float x) {            // f32 -> bf16 RNE
  unsigned u = __float_as_uint(x);
  return (u16)((u + 0x7FFFu + ((u >> 16) & 1u)) >> 16);
}
DINL float b2f(u16 b) { return __uint_as_float(((unsigned)b) << 16); }

// ================= CSR build =================
__global__ void deg_int_kernel(const int* __restrict__ dst, int* __restrict__ deg) {
  int t = blockIdx.x * 256 + threadIdx.x;
  if (t < E_) atomicAdd(&deg[dst[t]], 1);
}

__global__ __launch_bounds__(1024) void scan_kernel(const int* __restrict__ deg,
                                                    int* __restrict__ rowptr, int n) {
  __shared__ int sums[16];
  __shared__ int s_carry;
  const int tid = threadIdx.x, lane = tid & 63, wid = tid >> 6;
  if (tid == 0) s_carry = 0;
  __syncthreads();
  for (int base = 0; base < n; base += 1024) {
    int i = base + tid;
    int v = (i < n) ? deg[i] : 0;
    int x = v;
#pragma unroll
    for (int o = 1; o < 64; o <<= 1) { int y = __shfl_up(x, o); if (lane >= o) x += y; }
    if (lane == 63) sums[wid] = x;
    __syncthreads();
    if (wid == 0) {
      int s = (lane < 16) ? sums[lane] : 0;
#pragma unroll
      for (int o = 1; o < 16; o <<= 1) { int y = __shfl_up(s, o); if (lane >= o) s += y; }
      if (lane < 16) sums[lane] = s;
    }
    __syncthreads();
    int waveoff = wid ? sums[wid - 1] : 0;
    int incl = x + waveoff + s_carry;
    if (i < n) rowptr[i] = incl - v;
    __syncthreads();
    if (tid == 1023) s_carry = incl;
    __syncthreads();
  }
  if (tid == 0) rowptr[n] = s_carry;
}

__global__ void csr_fill(const int* __restrict__ src, const int* __restrict__ dst,
                         const int* __restrict__ rowptr, int* __restrict__ cursor,
                         int* __restrict__ colsrc) {
  int e = blockIdx.x * 256 + threadIdx.x;
  if (e >= E_) return;
  int d = dst[e];
  int pos = rowptr[d] + atomicAdd(&cursor[d], 1);
  colsrc[pos] = src[e];
}

// ================= packing =================
__global__ __launch_bounds__(256) void pack_feat(const float* __restrict__ f,
                                                 u16* __restrict__ o) {
  int t = blockIdx.x * 256 + threadIdx.x;        // one float4 per thread
  float4 v = ((const float4*)f)[t];
  short4v r;
  r[0] = (short)f2b(v.x); r[1] = (short)f2b(v.y);
  r[2] = (short)f2b(v.z); r[3] = (short)f2b(v.w);
  ((short4v*)o)[t] = r;
}

// pack all 7 weight matrices into MFMA B-fragment order:
// dst[((ct*(K/32)+ks)*64+lane)*8+j] = W[ks*32+(lane>>4)*8+j][ct*16+(lane&15)]
__global__ __launch_bounds__(256) void pack_w(
    const float* __restrict__ Wmt, const float* __restrict__ Wms,
    const float* __restrict__ W1s, const float* __restrict__ W1n,
    const float* __restrict__ W2s, const float* __restrict__ W2n,
    const float* __restrict__ g1Ws, const float* __restrict__ g1Wd,
    const float* __restrict__ g2Ws, const float* __restrict__ g2Wd,
    const float* __restrict__ W3, u16* __restrict__ dst) {
  int e = blockIdx.x * 256 + threadIdx.x;
  const float *Wa, *Wb = nullptr;
  int K1, K2 = 0, Ca, Cb = 0, st;
  if (e < 16384)       { Wa = Wmt;  K1 = 128; Ca = 128;           st = 0; }
  else if (e < 32768)  { Wa = Wms;  K1 = 128; Ca = 128;           st = 16384; }
  else if (e < 49152)  { Wa = W1s;  Wb = W1n; K1 = 128; K2 = 128; Ca = 64;  st = 32768; }
  else if (e < 57344)  { Wa = W2s;  Wb = W2n; K1 = 64;  K2 = 64;  Ca = 64;  st = 49152; }
  else if (e < 90112)  { Wa = g1Ws; Wb = g1Wd; K1 = 128; Ca = 128; Cb = 128; st = 57344; }
  else if (e < 106496) { Wa = g2Ws; Wb = g2Wd; K1 = 64;  Ca = 128; Cb = 128; st = 90112; }
  else                 { Wa = W3;   K1 = 192; Ca = 64;            st = 106496; }
  int el = e - st;
  int Kt = K1 + K2;
  int ct = el / (Kt * 16);
  int rem = el - ct * Kt * 16;
  int ks = rem >> 9, rem2 = rem & 511, lane = rem2 >> 3, j = rem2 & 7;
  int k = ks * 32 + ((lane >> 4) << 3) + j;
  int c = ct * 16 + (lane & 15);
  float v;
  if (k < K1) v = (c < Ca) ? Wa[k * Ca + c] : Wb[k * Cb + (c - Ca)];
  else        v = Wb[(k - K1) * Ca + c];
  dst[e] = f2b(v);
}

// ================= MFMA GEMM =================
// block = 64 rows x C cols, 4 waves, wave w owns rows [16w,16w+16)
// EPI: 0 plain bf16, 1 mask(sigmoid*feat), 2 gelu*drop, 3 gelu, 4 leaky+l2norm(f32)
template <int K1, int K2, int C, int EPI>
__global__ __launch_bounds__(256) void gemm_mfma(
    const u16* __restrict__ A1, const u16* __restrict__ A2,
    const u16* __restrict__ Wp, const float* __restrict__ bias,
    const u16* __restrict__ mulb, const float* __restrict__ mulf,
    void* __restrict__ outv) {
  constexpr int K = K1 + K2, SK = K + 8, KS = K / 32, CT = C / 16;
  __shared__ u16 alds[64 * SK];
  const int tid = threadIdx.x;
  const int wr0 = blockIdx.x * 64;
  for (int i = tid; i < 64 * (K1 / 8); i += 256) {
    int r = i / (K1 / 8), kc = i % (K1 / 8);
    int rg = wr0 + r; if (rg >= N_) rg = N_ - 1;
    short8 v = *(const short8*)(A1 + (long)rg * K1 + kc * 8);
    *(short8*)&alds[r * SK + kc * 8] = v;
  }
  if constexpr (K2 > 0) {
    for (int i = tid; i < 64 * (K2 / 8); i += 256) {
      int r = i / (K2 / 8), kc = i % (K2 / 8);
      int rg = wr0 + r; if (rg >= N_) rg = N_ - 1;
      short8 v = *(const short8*)(A2 + (long)rg * K2 + kc * 8);
      *(short8*)&alds[r * SK + K1 + kc * 8] = v;
    }
  }
  __syncthreads();
  const int w = tid >> 6, l = tid & 63;
  f32x4 acc[CT];
#pragma unroll
  for (int ct = 0; ct < CT; ++ct) acc[ct] = (f32x4){0.f, 0.f, 0.f, 0.f};
  const int arow = w * 16 + (l & 15);
#pragma unroll
  for (int ks = 0; ks < KS; ++ks) {
    short8 av = *(const short8*)&alds[arow * SK + ks * 32 + ((l >> 4) << 3)];
    bf16x8 af = __builtin_bit_cast(bf16x8, av);
#pragma unroll
    for (int ct = 0; ct < CT; ++ct) {
      short8 bv = *(const short8*)(Wp + ((size_t)(ct * KS + ks) * 64 + l) * 8);
      bf16x8 bfr = __builtin_bit_cast(bf16x8, bv);
      acc[ct] = __builtin_amdgcn_mfma_f32_16x16x32_bf16(af, bfr, acc[ct], 0, 0, 0);
    }
  }
  const int rbase = wr0 + w * 16 + ((l >> 4) << 2);
  const int cb = l & 15;
  if constexpr (EPI == 0) {
    u16* out = (u16*)outv;
#pragma unroll
    for (int ct = 0; ct < CT; ++ct)
#pragma unroll
      for (int r = 0; r < 4; ++r) {
        int row = rbase + r;
        if (row < N_) out[(long)row * C + ct * 16 + cb] = f2b(acc[ct][r]);
      }
  } else if constexpr (EPI == 1) {
    u16* out = (u16*)outv;
#pragma unroll
    for (int ct = 0; ct < CT; ++ct) {
      float bv = bias[ct * 16 + cb];
#pragma unroll
      for (int r = 0; r < 4; ++r) {
        int row = rbase + r;
        if (row < N_) {
          float x = acc[ct][r] + bv;
          float fv = b2f(mulb[(long)row * C + ct * 16 + cb]);
          out[(long)row * C + ct * 16 + cb] = f2b(fv * sigmoid_f(x));
        }
      }
    }
  } else if constexpr (EPI == 2 || EPI == 3) {
    u16* out = (u16*)outv;
#pragma unroll
    for (int ct = 0; ct < CT; ++ct) {
      float bv = bias[ct * 16 + cb];
#pragma unroll
      for (int r = 0; r < 4; ++r) {
        int row = rbase + r;
        if (row < N_) {
          float g = gelu_f(acc[ct][r] + bv);
          if constexpr (EPI == 2) g *= mulf[(long)row * C + ct * 16 + cb];
          out[(long)row * C + ct * 16 + cb] = f2b(g);
        }
      }
    }
  } else {
    float* out = (float*)outv;
#pragma unroll
    for (int r = 0; r < 4; ++r) {
      int row = rbase + r;
      float xv[CT];
      float ss = 0.f;
#pragma unroll
      for (int ct = 0; ct < CT; ++ct) {
        float x = acc[ct][r] + bias[ct * 16 + cb];
        x = x > 0.f ? x : 0.01f * x;
        xv[ct] = x; ss += x * x;
      }
#pragma unroll
      for (int o = 1; o < 16; o <<= 1) ss += __shfl_xor(ss, o);
      float inv = 1.f / fmaxf(sqrtf(ss), 1e-12f);
      if (row < N_)
#pragma unroll
        for (int ct = 0; ct < CT; ++ct) out[(long)row * C + ct * 16 + cb] = xv[ct] * inv;
    }
  }
}

// ================= SAGE gather (bf16 in/out, /deg fused) =================
template <int K>
__global__ __launch_bounds__(256) void gather_bf(const u16* __restrict__ h,
    const int* __restrict__ rowptr, const int* __restrict__ colsrc,
    u16* __restrict__ out) {
  int node = blockIdx.x * 4 + (threadIdx.x >> 6);
  int lane = threadIdx.x & 63;
  if (node >= N_) return;
  int beg = rowptr[node], end = rowptr[node + 1];
  float inv = 1.f / fmaxf((float)(end - beg), 1.f);
  if constexpr (K == 128) {
    float a0 = 0.f, a1 = 0.f;
    for (int j = beg; j < end; ++j) {
      int s = colsrc[j];
      a0 += b2f(h[(long)s * 128 + lane]);
      a1 += b2f(h[(long)s * 128 + 64 + lane]);
    }
    out[(long)node * 128 + lane] = f2b(a0 * inv);
    out[(long)node * 128 + 64 + lane] = f2b(a1 * inv);
  } else {
    float a0 = 0.f;
    for (int j = beg; j < end; ++j) a0 += b2f(h[(long)colsrc[j] * 64 + lane]);
    out[(long)node * 64 + lane] = f2b(a0 * inv);
  }
}

// ================= fused GATv2 (bf16 fs/fd, online softmax) =================
// fsfd row: [fs head0(64) | fs head1(64) | fd head0(64) | fd head1(64)]
template <bool LAYER1>
__global__ __launch_bounds__(256) void gat_fused(const u16* __restrict__ fsfd,
    const int* __restrict__ rowptr, const int* __restrict__ colsrc,
    const float* __restrict__ attn, const float* __restrict__ bias,
    const float* __restrict__ drop, void* __restrict__ outv) {
  int node = blockIdx.x * 4 + (threadIdx.x >> 6);
  int lane = threadIdx.x & 63;
  if (node >= N_) return;
  const float a0 = attn[lane], a1 = attn[64 + lane];
  const float fd0 = b2f(fsfd[(long)node * 256 + 128 + lane]);
  const float fd1 = b2f(fsfd[(long)node * 256 + 192 + lane]);
  float m0 = -INFINITY, m1 = -INFINITY;
  float d0 = 0.f, d1 = 0.f, acc0 = 0.f, acc1 = 0.f;
  const int beg = rowptr[node], end = rowptr[node + 1];
  for (int j = beg; j < end; ++j) {
    int s = colsrc[j];
    float f0 = b2f(fsfd[(long)s * 256 + lane]);
    float f1 = b2f(fsfd[(long)s * 256 + 64 + lane]);
    float x0 = f0 + fd0; x0 = x0 > 0.f ? x0 : 0.2f * x0;
    float x1 = f1 + fd1; x1 = x1 > 0.f ? x1 : 0.2f * x1;
    float p0 = x0 * a0, p1 = x1 * a1;
#pragma unroll
    for (int o = 32; o; o >>= 1) { p0 += __shfl_xor(p0, o); p1 += __shfl_xor(p1, o); }
    float nm0 = fmaxf(m0, p0), nm1 = fmaxf(m1, p1);
    float s0 = expf(m0 - nm0), s1 = expf(m1 - nm1);
    float e0 = expf(p0 - nm0), e1 = expf(p1 - nm1);
    d0 = d0 * s0 + e0;       d1 = d1 * s1 + e1;
    acc0 = acc0 * s0 + e0 * f0;
    acc1 = acc1 * s1 + e1 * f1;
    m0 = nm0; m1 = nm1;
  }
  float o0 = bias[lane]      + (d0 > 0.f ? acc0 / d0 : 0.f);
  float o1 = bias[64 + lane] + (d1 > 0.f ? acc1 / d1 : 0.f);
  float v = 0.5f * (gelu_f(o0) + gelu_f(o1));
  if constexpr (LAYER1) {
    ((u16*)outv)[(long)node * 64 + lane] = f2b(v * drop[(long)node * 64 + lane]);
  } else {
    float ss = v * v;
#pragma unroll
    for (int o = 32; o; o >>= 1) ss += __shfl_xor(ss, o);
    ((float*)outv)[(long)node * 64 + lane] = v / fmaxf(sqrtf(ss), 1e-12f);
  }
}

extern "C" void kernel_launch(void* const* d_in, const int* in_sizes, int n_in,
                              void* d_out, int out_size, void* d_ws, size_t ws_size,
                              hipStream_t stream) {
  const float* feat = (const float*)d_in[0];
  const int*   esrc = (const int*)d_in[1];
  const int*   edst = (const int*)d_in[2];
  const float* Wmt = (const float*)d_in[3],  *bmt = (const float*)d_in[4];
  const float* Wms = (const float*)d_in[5],  *bms = (const float*)d_in[6];
  const float* W1s = (const float*)d_in[7],  *W1n = (const float*)d_in[8],  *b1 = (const float*)d_in[9];
  const float* W2s = (const float*)d_in[10], *W2n = (const float*)d_in[11], *b2 = (const float*)d_in[12];
  const float* g1Ws = (const float*)d_in[13], *g1Wd = (const float*)d_in[14];
  const float* g1a  = (const float*)d_in[15], *g1b  = (const float*)d_in[16];
  const float* g2Ws = (const float*)d_in[17], *g2Wd = (const float*)d_in[18];
  const float* g2a  = (const float*)d_in[19], *g2b  = (const float*)d_in[20];
  const float* W3  = (const float*)d_in[21], *b3 = (const float*)d_in[22];
  const float* dropt = (const float*)d_in[23], *drops = (const float*)d_in[24];

  float* out_t = (float*)d_out;
  float* out_s = out_t + (long)N_ * 64;

  // workspace (u16 units)
  u16* wsh = (u16*)d_ws;
  u16* featbf = wsh;                 // N*128
  u16* hbuf   = wsh +  6400000;      // N*128  (h_t / h_s)
  u16* hn     = wsh + 12800000;      // N*128
  u16* h1     = wsh + 19200000;      // N*64
  u16* hn2    = wsh + 22400000;      // N*64
  u16* h2     = wsh + 25600000;      // N*64
  u16* hs1    = wsh + 28800000;      // N*64
  u16* fsfd   = wsh + 32000000;      // N*256
  u16* Wpk    = wsh + 44800000;      // 118784
  int* degi   = (int*)(wsh + 44918784);  // N
  int* rowptr = degi + N_;               // N+1
  int* cursor = rowptr + N_ + 1;         // N
  int* colsrc = cursor + N_;             // E

  const u16* WpMT = Wpk;
  const u16* WpMS = Wpk + 16384;
  const u16* WpS1 = Wpk + 32768;
  const u16* WpS2 = Wpk + 49152;
  const u16* WpG1 = Wpk + 57344;
  const u16* WpG2 = Wpk + 90112;
  const u16* WpW3 = Wpk + 106496;

  constexpr int GB = (N_ + 63) / 64;   // 782 gemm blocks

  // ---- CSR + packing ----
  hipMemsetAsync(degi, 0, (size_t)(3 * N_ + 1) * sizeof(int), stream);
  deg_int_kernel<<<(E_ + 255) / 256, 256, 0, stream>>>(edst, degi);
  scan_kernel<<<1, 1024, 0, stream>>>(degi, rowptr, N_);
  csr_fill<<<(E_ + 255) / 256, 256, 0, stream>>>(esrc, edst, rowptr, cursor, colsrc);
  pack_feat<<<N_ * 128 / 4 / 256, 256, 0, stream>>>(feat, featbf);
  pack_w<<<464, 256, 0, stream>>>(Wmt, Wms, W1s, W1n, W2s, W2n,
                                  g1Ws, g1Wd, g2Ws, g2Wd, W3, Wpk);

  // ---- topology branch (SAGE) ----
  gemm_mfma<128, 0, 128, 1><<<GB, 256, 0, stream>>>(featbf, nullptr, WpMT, bmt, featbf, nullptr, hbuf);
  gather_bf<128><<<N_ / 4, 256, 0, stream>>>(hbuf, rowptr, colsrc, hn);
  gemm_mfma<128, 128, 64, 2><<<GB, 256, 0, stream>>>(hbuf, hn, WpS1, b1, nullptr, dropt, h1);
  gather_bf<64><<<N_ / 4, 256, 0, stream>>>(h1, rowptr, colsrc, hn2);
  gemm_mfma<64, 64, 64, 3><<<GB, 256, 0, stream>>>(h1, hn2, WpS2, b2, nullptr, nullptr, h2);
  gemm_mfma<64, 128, 64, 4><<<GB, 256, 0, stream>>>(h2, featbf, WpW3, b3, nullptr, nullptr, out_t);

  // ---- semantic branch (GATv2) ----
  gemm_mfma<128, 0, 128, 1><<<GB, 256, 0, stream>>>(featbf, nullptr, WpMS, bms, featbf, nullptr, hbuf);
  gemm_mfma<128, 0, 256, 0><<<GB, 256, 0, stream>>>(hbuf, nullptr, WpG1, nullptr, nullptr, nullptr, fsfd);
  gat_fused<true><<<N_ / 4, 256, 0, stream>>>(fsfd, rowptr, colsrc, g1a, g1b, drops, hs1);
  gemm_mfma<64, 0, 256, 0><<<GB, 256, 0, stream>>>(hs1, nullptr, WpG2, nullptr, nullptr, nullptr, fsfd);
  gat_fused<false><<<N_ / 4, 256, 0, stream>>>(fsfd, rowptr, colsrc, g2a, g2b, nullptr, out_s);
}

// Round 4
// 486.679 us; speedup vs baseline: 5.0816x; 1.0464x over previous
//
#include <hip/hip_runtime.h>
#include <math.h>

constexpr int N_  = 50000;
constexpr int E_  = 500000;

typedef unsigned short u16;
typedef unsigned int u32;
typedef short short8 __attribute__((ext_vector_type(8)));
typedef __bf16 bf16x8 __attribute__((ext_vector_type(8)));
typedef float f32x4 __attribute__((ext_vector_type(4)));
typedef short short4v __attribute__((ext_vector_type(4)));

#define DINL __device__ __forceinline__

DINL float gelu_f(float x) { return 0.5f * x * (1.f + erff(x * 0.70710678118654752f)); }
DINL float sigmoid_f(float x) { return 1.f / (1.f + expf(-x)); }
DINL u16 f2b(float x) {            // f32 -> bf16 RNE
  unsigned u = __float_as_uint(x);
  return (u16)((u + 0x7FFFu + ((u >> 16) & 1u)) >> 16);
}
DINL float b2f(u16 b) { return __uint_as_float(((unsigned)b) << 16); }

// ================= CSR build =================
__global__ void deg_int_kernel(const int* __restrict__ dst, int* __restrict__ deg) {
  int t = blockIdx.x * 256 + threadIdx.x;
  if (t < E_) atomicAdd(&deg[dst[t]], 1);
}

// single-pass scan: each thread owns a contiguous chunk
__global__ __launch_bounds__(1024) void scan_kernel(const int* __restrict__ deg,
                                                    int* __restrict__ rowptr, int n) {
  constexpr int CH = 49;   // ceil(50000/1024)
  __shared__ int sums[16];
  const int tid = threadIdx.x, lane = tid & 63, wid = tid >> 6;
  const int t0 = tid * CH;
  int tsum = 0;
  for (int i = 0; i < CH; ++i) { int idx = t0 + i; if (idx < n) tsum += deg[idx]; }
  int x = tsum;
#pragma unroll
  for (int o = 1; o < 64; o <<= 1) { int y = __shfl_up(x, o); if (lane >= o) x += y; }
  if (lane == 63) sums[wid] = x;
  __syncthreads();
  if (wid == 0) {
    int s = (lane < 16) ? sums[lane] : 0;
#pragma unroll
    for (int o = 1; o < 16; o <<= 1) { int y = __shfl_up(s, o); if (lane >= o) s += y; }
    if (lane < 16) sums[lane] = s;
  }
  __syncthreads();
  int incl = x + (wid ? sums[wid - 1] : 0);
  int run = incl - tsum;
  for (int i = 0; i < CH; ++i) {
    int idx = t0 + i;
    if (idx < n) { rowptr[idx] = run; run += deg[idx]; }
  }
  if (tid == 1023) rowptr[n] = incl;
}

__global__ void csr_fill(const int* __restrict__ src, const int* __restrict__ dst,
                         const int* __restrict__ rowptr, int* __restrict__ cursor,
                         int* __restrict__ colsrc) {
  int e = blockIdx.x * 256 + threadIdx.x;
  if (e >= E_) return;
  int d = dst[e];
  int pos = rowptr[d] + atomicAdd(&cursor[d], 1);
  colsrc[pos] = src[e];
}

// ================= packing =================
__global__ __launch_bounds__(256) void pack_feat(const float* __restrict__ f,
                                                 u16* __restrict__ o) {
  int t = blockIdx.x * 256 + threadIdx.x;
  float4 v = ((const float4*)f)[t];
  short4v r;
  r[0] = (short)f2b(v.x); r[1] = (short)f2b(v.y);
  r[2] = (short)f2b(v.z); r[3] = (short)f2b(v.w);
  ((short4v*)o)[t] = r;
}

// pack weights into MFMA B-fragment order:
// dst[((ct*(K/32)+ks)*64+lane)*8+j] = W[ks*32+(lane>>4)*8+j][ct*16+(lane&15)]
__global__ __launch_bounds__(256) void pack_w(
    const float* __restrict__ Wmt, const float* __restrict__ Wms,
    const float* __restrict__ W1s, const float* __restrict__ W1n,
    const float* __restrict__ W2s, const float* __restrict__ W2n,
    const float* __restrict__ g1Ws, const float* __restrict__ g1Wd,
    const float* __restrict__ g2Ws, const float* __restrict__ g2Wd,
    const float* __restrict__ W3, u16* __restrict__ dst) {
  int e = blockIdx.x * 256 + threadIdx.x;
  const float *Wa, *Wb = nullptr;
  int K1, K2 = 0, Ca, Cb = 0, st;
  if (e < 16384)       { Wa = Wmt;  K1 = 128; Ca = 128;           st = 0; }
  else if (e < 32768)  { Wa = Wms;  K1 = 128; Ca = 128;           st = 16384; }
  else if (e < 49152)  { Wa = W1s;  Wb = W1n; K1 = 128; K2 = 128; Ca = 64;  st = 32768; }
  else if (e < 57344)  { Wa = W2s;  Wb = W2n; K1 = 64;  K2 = 64;  Ca = 64;  st = 49152; }
  else if (e < 90112)  { Wa = g1Ws; Wb = g1Wd; K1 = 128; Ca = 128; Cb = 128; st = 57344; }
  else if (e < 106496) { Wa = g2Ws; Wb = g2Wd; K1 = 64;  Ca = 128; Cb = 128; st = 90112; }
  else                 { Wa = W3;   K1 = 192; Ca = 64;            st = 106496; }
  int el = e - st;
  int Kt = K1 + K2;
  int ct = el / (Kt * 16);
  int rem = el - ct * Kt * 16;
  int ks = rem >> 9, rem2 = rem & 511, lane = rem2 >> 3, j = rem2 & 7;
  int k = ks * 32 + ((lane >> 4) << 3) + j;
  int c = ct * 16 + (lane & 15);
  float v;
  if (k < K1) v = (c < Ca) ? Wa[k * Ca + c] : Wb[k * Cb + (c - Ca)];
  else        v = Wb[(k - K1) * Ca + c];
  dst[e] = f2b(v);
}

// ================= MFMA GEMM =================
// EPI: 0 plain bf16, 1 mask(sigmoid*feat), 2 gelu*drop, 3 gelu, 4 leaky+l2norm(f32)
template <int K1, int K2, int C, int EPI>
__global__ __launch_bounds__(256) void gemm_mfma(
    const u16* __restrict__ A1, const u16* __restrict__ A2,
    const u16* __restrict__ Wp, const float* __restrict__ bias,
    const u16* __restrict__ mulb, const float* __restrict__ mulf,
    void* __restrict__ outv) {
  constexpr int K = K1 + K2, SK = K + 8, KS = K / 32, CT = C / 16;
  __shared__ u16 alds[64 * SK];
  const int tid = threadIdx.x;
  const int wr0 = blockIdx.x * 64;
  for (int i = tid; i < 64 * (K1 / 8); i += 256) {
    int r = i / (K1 / 8), kc = i % (K1 / 8);
    int rg = wr0 + r; if (rg >= N_) rg = N_ - 1;
    short8 v = *(const short8*)(A1 + (long)rg * K1 + kc * 8);
    *(short8*)&alds[r * SK + kc * 8] = v;
  }
  if constexpr (K2 > 0) {
    for (int i = tid; i < 64 * (K2 / 8); i += 256) {
      int r = i / (K2 / 8), kc = i % (K2 / 8);
      int rg = wr0 + r; if (rg >= N_) rg = N_ - 1;
      short8 v = *(const short8*)(A2 + (long)rg * K2 + kc * 8);
      *(short8*)&alds[r * SK + K1 + kc * 8] = v;
    }
  }
  __syncthreads();
  const int w = tid >> 6, l = tid & 63;
  f32x4 acc[CT];
#pragma unroll
  for (int ct = 0; ct < CT; ++ct) acc[ct] = (f32x4){0.f, 0.f, 0.f, 0.f};
  const int arow = w * 16 + (l & 15);
#pragma unroll
  for (int ks = 0; ks < KS; ++ks) {
    short8 av = *(const short8*)&alds[arow * SK + ks * 32 + ((l >> 4) << 3)];
    bf16x8 af = __builtin_bit_cast(bf16x8, av);
#pragma unroll
    for (int ct = 0; ct < CT; ++ct) {
      short8 bv = *(const short8*)(Wp + ((size_t)(ct * KS + ks) * 64 + l) * 8);
      bf16x8 bfr = __builtin_bit_cast(bf16x8, bv);
      acc[ct] = __builtin_amdgcn_mfma_f32_16x16x32_bf16(af, bfr, acc[ct], 0, 0, 0);
    }
  }
  const int rbase = wr0 + w * 16 + ((l >> 4) << 2);
  const int cb = l & 15;
  if constexpr (EPI == 0) {
    u16* out = (u16*)outv;
#pragma unroll
    for (int ct = 0; ct < CT; ++ct)
#pragma unroll
      for (int r = 0; r < 4; ++r) {
        int row = rbase + r;
        if (row < N_) out[(long)row * C + ct * 16 + cb] = f2b(acc[ct][r]);
      }
  } else if constexpr (EPI == 1) {
    u16* out = (u16*)outv;
#pragma unroll
    for (int ct = 0; ct < CT; ++ct) {
      float bv = bias[ct * 16 + cb];
#pragma unroll
      for (int r = 0; r < 4; ++r) {
        int row = rbase + r;
        if (row < N_) {
          float x = acc[ct][r] + bv;
          float fv = b2f(mulb[(long)row * C + ct * 16 + cb]);
          out[(long)row * C + ct * 16 + cb] = f2b(fv * sigmoid_f(x));
        }
      }
    }
  } else if constexpr (EPI == 2 || EPI == 3) {
    u16* out = (u16*)outv;
#pragma unroll
    for (int ct = 0; ct < CT; ++ct) {
      float bv = bias[ct * 16 + cb];
#pragma unroll
      for (int r = 0; r < 4; ++r) {
        int row = rbase + r;
        if (row < N_) {
          float g = gelu_f(acc[ct][r] + bv);
          if constexpr (EPI == 2) g *= mulf[(long)row * C + ct * 16 + cb];
          out[(long)row * C + ct * 16 + cb] = f2b(g);
        }
      }
    }
  } else {
    float* out = (float*)outv;
#pragma unroll
    for (int r = 0; r < 4; ++r) {
      int row = rbase + r;
      float xv[CT];
      float ss = 0.f;
#pragma unroll
      for (int ct = 0; ct < CT; ++ct) {
        float x = acc[ct][r] + bias[ct * 16 + cb];
        x = x > 0.f ? x : 0.01f * x;
        xv[ct] = x; ss += x * x;
      }
#pragma unroll
      for (int o = 1; o < 16; o <<= 1) ss += __shfl_xor(ss, o);
      float inv = 1.f / fmaxf(sqrtf(ss), 1e-12f);
      if (row < N_)
#pragma unroll
        for (int ct = 0; ct < CT; ++ct) out[(long)row * C + ct * 16 + cb] = xv[ct] * inv;
    }
  }
}

// ================= SAGE gather (ushort2/lane, /deg fused) =================
__global__ __launch_bounds__(256) void gather_bf128(const u16* __restrict__ h,
    const int* __restrict__ rowptr, const int* __restrict__ colsrc,
    u16* __restrict__ out) {
  int node = blockIdx.x * 4 + (threadIdx.x >> 6);
  int lane = threadIdx.x & 63;
  if (node >= N_) return;
  int beg = rowptr[node], end = rowptr[node + 1];
  float inv = 1.f / fmaxf((float)(end - beg), 1.f);
  float a0 = 0.f, a1 = 0.f;
  for (int j = beg; j < end; ++j) {
    int s = colsrc[j];
    u32 v = *(const u32*)(h + (long)s * 128 + 2 * lane);
    a0 += b2f((u16)(v & 0xffffu));
    a1 += b2f((u16)(v >> 16));
  }
  u32 r = (u32)f2b(a0 * inv) | ((u32)f2b(a1 * inv) << 16);
  *(u32*)(out + (long)node * 128 + 2 * lane) = r;
}

// K=64: two edges per wave iteration (lanes 0-31 edge j, 32-63 edge j+1)
__global__ __launch_bounds__(256) void gather_bf64(const u16* __restrict__ h,
    const int* __restrict__ rowptr, const int* __restrict__ colsrc,
    u16* __restrict__ out) {
  int node = blockIdx.x * 4 + (threadIdx.x >> 6);
  int lane = threadIdx.x & 63;
  if (node >= N_) return;
  int beg = rowptr[node], end = rowptr[node + 1];
  int half = lane >> 5, cl = lane & 31;
  float a0 = 0.f, a1 = 0.f;
  for (int j = beg + half; j < end; j += 2) {
    int s = colsrc[j];
    u32 v = *(const u32*)(h + (long)s * 64 + 2 * cl);
    a0 += b2f((u16)(v & 0xffffu));
    a1 += b2f((u16)(v >> 16));
  }
  a0 += __shfl_xor(a0, 32);
  a1 += __shfl_xor(a1, 32);
  if (lane < 32) {
    float inv = 1.f / fmaxf((float)(end - beg), 1.f);
    u32 r = (u32)f2b(a0 * inv) | ((u32)f2b(a1 * inv) << 16);
    *(u32*)(out + (long)node * 64 + 2 * lane) = r;
  }
}

// ================= fused GATv2 v2 =================
// split-lane layout: lane l owns cols {2l,2l+1}; lanes 0-31 = head0, 32-63 = head1.
// raw exp (logits bounded, no max needed); one __expf per edge.
template <bool LAYER1>
__global__ __launch_bounds__(256) void gat_fused(const u16* __restrict__ fsfd,
    const int* __restrict__ rowptr, const int* __restrict__ colsrc,
    const float* __restrict__ attn, const float* __restrict__ bias,
    const float* __restrict__ drop, void* __restrict__ outv) {
  int node = blockIdx.x * 4 + (threadIdx.x >> 6);
  int lane = threadIdx.x & 63;
  if (node >= N_) return;
  float2 av = *(const float2*)(attn + 2 * lane);
  u32 fdv = *(const u32*)(fsfd + (long)node * 256 + 128 + 2 * lane);
  float fd0 = b2f((u16)(fdv & 0xffffu)), fd1 = b2f((u16)(fdv >> 16));
  float d_own = 0.f, acc0 = 0.f, acc1 = 0.f;
  const int beg = rowptr[node], end = rowptr[node + 1];
  for (int j = beg; j < end; ++j) {
    int s = colsrc[j];
    u32 fv = *(const u32*)(fsfd + (long)s * 256 + 2 * lane);
    float f0 = b2f((u16)(fv & 0xffffu)), f1 = b2f((u16)(fv >> 16));
    float x0 = f0 + fd0; x0 = x0 > 0.f ? x0 : 0.2f * x0;
    float x1 = f1 + fd1; x1 = x1 > 0.f ? x1 : 0.2f * x1;
    float c = x0 * av.x + x1 * av.y;
#pragma unroll
    for (int o = 16; o; o >>= 1) c += __shfl_xor(c, o);   // per-half reduce -> head logit
    float e = __expf(c);
    d_own += e;
    acc0 += e * f0;
    acc1 += e * f1;
  }
  float2 bv = *(const float2*)(bias + 2 * lane);
  float inv = d_own > 0.f ? 1.f / d_own : 0.f;
  float g0 = gelu_f(bv.x + acc0 * inv);
  float g1 = gelu_f(bv.y + acc1 * inv);
  float v0 = 0.5f * (g0 + __shfl_xor(g0, 32));   // mean over heads
  float v1 = 0.5f * (g1 + __shfl_xor(g1, 32));
  if constexpr (LAYER1) {
    if (lane < 32) {
      float2 dv = *(const float2*)(drop + (long)node * 64 + 2 * lane);
      u32 r = (u32)f2b(v0 * dv.x) | ((u32)f2b(v1 * dv.y) << 16);
      *(u32*)((u16*)outv + (long)node * 64 + 2 * lane) = r;
    }
  } else {
    float ss = v0 * v0 + v1 * v1;
#pragma unroll
    for (int o = 16; o; o >>= 1) ss += __shfl_xor(ss, o);
    float sc = 1.f / fmaxf(sqrtf(ss), 1e-12f);
    if (lane < 32) {
      float2 r; r.x = v0 * sc; r.y = v1 * sc;
      *(float2*)((float*)outv + (long)node * 64 + 2 * lane) = r;
    }
  }
}

extern "C" void kernel_launch(void* const* d_in, const int* in_sizes, int n_in,
                              void* d_out, int out_size, void* d_ws, size_t ws_size,
                              hipStream_t stream) {
  const float* feat = (const float*)d_in[0];
  const int*   esrc = (const int*)d_in[1];
  const int*   edst = (const int*)d_in[2];
  const float* Wmt = (const float*)d_in[3],  *bmt = (const float*)d_in[4];
  const float* Wms = (const float*)d_in[5],  *bms = (const float*)d_in[6];
  const float* W1s = (const float*)d_in[7],  *W1n = (const float*)d_in[8],  *b1 = (const float*)d_in[9];
  const float* W2s = (const float*)d_in[10], *W2n = (const float*)d_in[11], *b2 = (const float*)d_in[12];
  const float* g1Ws = (const float*)d_in[13], *g1Wd = (const float*)d_in[14];
  const float* g1a  = (const float*)d_in[15], *g1b  = (const float*)d_in[16];
  const float* g2Ws = (const float*)d_in[17], *g2Wd = (const float*)d_in[18];
  const float* g2a  = (const float*)d_in[19], *g2b  = (const float*)d_in[20];
  const float* W3  = (const float*)d_in[21], *b3 = (const float*)d_in[22];
  const float* dropt = (const float*)d_in[23], *drops = (const float*)d_in[24];

  float* out_t = (float*)d_out;
  float* out_s = out_t + (long)N_ * 64;

  // workspace (u16 units)
  u16* wsh = (u16*)d_ws;
  u16* featbf = wsh;                 // N*128
  u16* hbuf   = wsh +  6400000;      // N*128
  u16* hn     = wsh + 12800000;      // N*128
  u16* h1     = wsh + 19200000;      // N*64
  u16* hn2    = wsh + 22400000;      // N*64
  u16* h2     = wsh + 25600000;      // N*64
  u16* hs1    = wsh + 28800000;      // N*64
  u16* fsfd   = wsh + 32000000;      // N*256
  u16* Wpk    = wsh + 44800000;      // 118784
  int* degi   = (int*)(wsh + 44918784);  // N
  int* rowptr = degi + N_;               // N+1
  int* cursor = rowptr + N_ + 1;         // N
  int* colsrc = cursor + N_;             // E

  const u16* WpMT = Wpk;
  const u16* WpMS = Wpk + 16384;
  const u16* WpS1 = Wpk + 32768;
  const u16* WpS2 = Wpk + 49152;
  const u16* WpG1 = Wpk + 57344;
  const u16* WpG2 = Wpk + 90112;
  const u16* WpW3 = Wpk + 106496;

  constexpr int GB = (N_ + 63) / 64;

  // ---- CSR + packing ----
  hipMemsetAsync(degi, 0, (size_t)(3 * N_ + 1) * sizeof(int), stream);
  deg_int_kernel<<<(E_ + 255) / 256, 256, 0, stream>>>(edst, degi);
  scan_kernel<<<1, 1024, 0, stream>>>(degi, rowptr, N_);
  csr_fill<<<(E_ + 255) / 256, 256, 0, stream>>>(esrc, edst, rowptr, cursor, colsrc);
  pack_feat<<<N_ * 128 / 4 / 256, 256, 0, stream>>>(feat, featbf);
  pack_w<<<464, 256, 0, stream>>>(Wmt, Wms, W1s, W1n, W2s, W2n,
                                  g1Ws, g1Wd, g2Ws, g2Wd, W3, Wpk);

  // ---- topology branch (SAGE) ----
  gemm_mfma<128, 0, 128, 1><<<GB, 256, 0, stream>>>(featbf, nullptr, WpMT, bmt, featbf, nullptr, hbuf);
  gather_bf128<<<N_ / 4, 256, 0, stream>>>(hbuf, rowptr, colsrc, hn);
  gemm_mfma<128, 128, 64, 2><<<GB, 256, 0, stream>>>(hbuf, hn, WpS1, b1, nullptr, dropt, h1);
  gather_bf64<<<N_ / 4, 256, 0, stream>>>(h1, rowptr, colsrc, hn2);
  gemm_mfma<64, 64, 64, 3><<<GB, 256, 0, stream>>>(h1, hn2, WpS2, b2, nullptr, nullptr, h2);
  gemm_mfma<64, 128, 64, 4><<<GB, 256, 0, stream>>>(h2, featbf, WpW3, b3, nullptr, nullptr, out_t);

  // ---- semantic branch (GATv2) ----
  gemm_mfma<128, 0, 128, 1><<<GB, 256, 0, stream>>>(featbf, nullptr, WpMS, bms, featbf, nullptr, hbuf);
  gemm_mfma<128, 0, 256, 0><<<GB, 256, 0, stream>>>(hbuf, nullptr, WpG1, nullptr, nullptr, nullptr, fsfd);
  gat_fused<true><<<N_ / 4, 256, 0, stream>>>(fsfd, rowptr, colsrc, g1a, g1b, drops, hs1);
  gemm_mfma<64, 0, 256, 0><<<GB, 256, 0, stream>>>(hs1, nullptr, WpG2, nullptr, nullptr, nullptr, fsfd);
  gat_fused<false><<<N_ / 4, 256, 0, stream>>>(fsfd, rowptr, colsrc, g2a, g2b, nullptr, out_s);
}

// Round 5
// 387.146 us; speedup vs baseline: 6.3880x; 1.2571x over previous
//
#include <hip/hip_runtime.h>
#include <math.h>

constexpr int N_  = 50000;
constexpr int E_  = 500000;
constexpr int NB_ = (N_ + 255) / 256;   // 196 scan blocks

typedef unsigned short u16;
typedef unsigned int u32;
typedef short short8 __attribute__((ext_vector_type(8)));
typedef __bf16 bf16x8 __attribute__((ext_vector_type(8)));
typedef float f32x4 __attribute__((ext_vector_type(4)));
typedef short short4v __attribute__((ext_vector_type(4)));

#define DINL __device__ __forceinline__

DINL float gelu_f(float x) { return 0.5f * x * (1.f + erff(x * 0.70710678118654752f)); }
DINL float sigmoid_f(float x) { return 1.f / (1.f + expf(-x)); }
DINL u16 f2b(float x) {            // f32 -> bf16 RNE
  unsigned u = __float_as_uint(x);
  return (u16)((u + 0x7FFFu + ((u >> 16) & 1u)) >> 16);
}
DINL float b2f(u16 b) { return __uint_as_float(((unsigned)b) << 16); }

// ================= CSR build =================
__global__ void deg_int_kernel(const int* __restrict__ dst, int* __restrict__ deg) {
  int t = blockIdx.x * 256 + threadIdx.x;
  if (t < E_) atomicAdd(&deg[dst[t]], 1);
}

// S1: per-block exclusive scan of 256 elements + block total
__global__ __launch_bounds__(256) void scan_local(const int* __restrict__ deg,
    int* __restrict__ rowptr, int* __restrict__ bsum) {
  __shared__ int sums[4];
  const int tid = threadIdx.x, lane = tid & 63, wid = tid >> 6;
  const int i = blockIdx.x * 256 + tid;
  int v = (i < N_) ? deg[i] : 0;
  int x = v;
#pragma unroll
  for (int o = 1; o < 64; o <<= 1) { int y = __shfl_up(x, o); if (lane >= o) x += y; }
  if (lane == 63) sums[wid] = x;
  __syncthreads();
  int woff = 0;
#pragma unroll
  for (int w = 0; w < 3; ++w) if (w < wid) woff += sums[w];
  if (i < N_) rowptr[i] = x - v + woff;
  if (tid == 255) bsum[blockIdx.x] = woff + x;
}

// S2: scan the 196 block totals (single block)
__global__ __launch_bounds__(256) void scan_block(const int* __restrict__ bsum,
                                                  int* __restrict__ bpre) {
  __shared__ int sums[4];
  const int tid = threadIdx.x, lane = tid & 63, wid = tid >> 6;
  int v = (tid < NB_) ? bsum[tid] : 0;
  int x = v;
#pragma unroll
  for (int o = 1; o < 64; o <<= 1) { int y = __shfl_up(x, o); if (lane >= o) x += y; }
  if (lane == 63) sums[wid] = x;
  __syncthreads();
  int woff = 0;
#pragma unroll
  for (int w = 0; w < 3; ++w) if (w < wid) woff += sums[w];
  if (tid < NB_) bpre[tid] = x - v + woff;
  if (tid == 255) bpre[NB_] = woff + x;   // grand total
}

// S3: add block prefixes; write rowptr[N]
__global__ __launch_bounds__(256) void scan_add(int* __restrict__ rowptr,
                                                const int* __restrict__ bpre) {
  int i = blockIdx.x * 256 + threadIdx.x;
  if (i < N_) rowptr[i] += bpre[i >> 8];
  else if (i == N_) rowptr[N_] = bpre[NB_];
}

__global__ void csr_fill(const int* __restrict__ src, const int* __restrict__ dst,
                         const int* __restrict__ rowptr, int* __restrict__ cursor,
                         int* __restrict__ colsrc) {
  int e = blockIdx.x * 256 + threadIdx.x;
  if (e >= E_) return;
  int d = dst[e];
  int pos = rowptr[d] + atomicAdd(&cursor[d], 1);
  colsrc[pos] = src[e];
}

// ================= packing =================
__global__ __launch_bounds__(256) void pack_feat(const float* __restrict__ f,
                                                 u16* __restrict__ o) {
  int t = blockIdx.x * 256 + threadIdx.x;
  float4 v = ((const float4*)f)[t];
  short4v r;
  r[0] = (short)f2b(v.x); r[1] = (short)f2b(v.y);
  r[2] = (short)f2b(v.z); r[3] = (short)f2b(v.w);
  ((short4v*)o)[t] = r;
}

// pack weights into MFMA B-fragment order:
// dst[((ct*(K/32)+ks)*64+lane)*8+j] = W[ks*32+(lane>>4)*8+j][ct*16+(lane&15)]
__global__ __launch_bounds__(256) void pack_w(
    const float* __restrict__ Wmt, const float* __restrict__ Wms,
    const float* __restrict__ W1s, const float* __restrict__ W1n,
    const float* __restrict__ W2s, const float* __restrict__ W2n,
    const float* __restrict__ g1Ws, const float* __restrict__ g1Wd,
    const float* __restrict__ g2Ws, const float* __restrict__ g2Wd,
    const float* __restrict__ W3, u16* __restrict__ dst) {
  int e = blockIdx.x * 256 + threadIdx.x;
  const float *Wa, *Wb = nullptr;
  int K1, K2 = 0, Ca, Cb = 0, st;
  if (e < 16384)       { Wa = Wmt;  K1 = 128; Ca = 128;           st = 0; }
  else if (e < 32768)  { Wa = Wms;  K1 = 128; Ca = 128;           st = 16384; }
  else if (e < 49152)  { Wa = W1s;  Wb = W1n; K1 = 128; K2 = 128; Ca = 64;  st = 32768; }
  else if (e < 57344)  { Wa = W2s;  Wb = W2n; K1 = 64;  K2 = 64;  Ca = 64;  st = 49152; }
  else if (e < 90112)  { Wa = g1Ws; Wb = g1Wd; K1 = 128; Ca = 128; Cb = 128; st = 57344; }
  else if (e < 106496) { Wa = g2Ws; Wb = g2Wd; K1 = 64;  Ca = 128; Cb = 128; st = 90112; }
  else                 { Wa = W3;   K1 = 192; Ca = 64;            st = 106496; }
  int el = e - st;
  int Kt = K1 + K2;
  int ct = el / (Kt * 16);
  int rem = el - ct * Kt * 16;
  int ks = rem >> 9, rem2 = rem & 511, lane = rem2 >> 3, j = rem2 & 7;
  int k = ks * 32 + ((lane >> 4) << 3) + j;
  int c = ct * 16 + (lane & 15);
  float v;
  if (k < K1) v = (c < Ca) ? Wa[k * Ca + c] : Wb[k * Cb + (c - Ca)];
  else        v = Wb[(k - K1) * Ca + c];
  dst[e] = f2b(v);
}

// ================= MFMA GEMM =================
// EPI: 0 plain bf16, 2 gelu*drop, 3 gelu, 4 leaky+l2norm(f32),
//      5 dual-mask: cols<128 -> outv (bias,sigmoid*mulb), cols>=128 -> outv2 (bias2,...)
template <int K1, int K2, int C, int EPI>
__global__ __launch_bounds__(256) void gemm_mfma(
    const u16* __restrict__ A1, const u16* __restrict__ A2,
    const u16* __restrict__ Wp, const float* __restrict__ bias,
    const float* __restrict__ bias2, const u16* __restrict__ mulb,
    const float* __restrict__ mulf, void* __restrict__ outv,
    void* __restrict__ outv2) {
  constexpr int K = K1 + K2, SK = K + 8, KS = K / 32, CT = C / 16;
  __shared__ u16 alds[64 * SK];
  const int tid = threadIdx.x;
  const int wr0 = blockIdx.x * 64;
  for (int i = tid; i < 64 * (K1 / 8); i += 256) {
    int r = i / (K1 / 8), kc = i % (K1 / 8);
    int rg = wr0 + r; if (rg >= N_) rg = N_ - 1;
    short8 v = *(const short8*)(A1 + (long)rg * K1 + kc * 8);
    *(short8*)&alds[r * SK + kc * 8] = v;
  }
  if constexpr (K2 > 0) {
    for (int i = tid; i < 64 * (K2 / 8); i += 256) {
      int r = i / (K2 / 8), kc = i % (K2 / 8);
      int rg = wr0 + r; if (rg >= N_) rg = N_ - 1;
      short8 v = *(const short8*)(A2 + (long)rg * K2 + kc * 8);
      *(short8*)&alds[r * SK + K1 + kc * 8] = v;
    }
  }
  __syncthreads();
  const int w = tid >> 6, l = tid & 63;
  f32x4 acc[CT];
#pragma unroll
  for (int ct = 0; ct < CT; ++ct) acc[ct] = (f32x4){0.f, 0.f, 0.f, 0.f};
  const int arow = w * 16 + (l & 15);
#pragma unroll
  for (int ks = 0; ks < KS; ++ks) {
    short8 av = *(const short8*)&alds[arow * SK + ks * 32 + ((l >> 4) << 3)];
    bf16x8 af = __builtin_bit_cast(bf16x8, av);
#pragma unroll
    for (int ct = 0; ct < CT; ++ct) {
      short8 bv = *(const short8*)(Wp + ((size_t)(ct * KS + ks) * 64 + l) * 8);
      bf16x8 bfr = __builtin_bit_cast(bf16x8, bv);
      acc[ct] = __builtin_amdgcn_mfma_f32_16x16x32_bf16(af, bfr, acc[ct], 0, 0, 0);
    }
  }
  const int rbase = wr0 + w * 16 + ((l >> 4) << 2);
  const int cb = l & 15;
  if constexpr (EPI == 0) {
    u16* out = (u16*)outv;
#pragma unroll
    for (int ct = 0; ct < CT; ++ct)
#pragma unroll
      for (int r = 0; r < 4; ++r) {
        int row = rbase + r;
        if (row < N_) out[(long)row * C + ct * 16 + cb] = f2b(acc[ct][r]);
      }
  } else if constexpr (EPI == 2 || EPI == 3) {
    u16* out = (u16*)outv;
#pragma unroll
    for (int ct = 0; ct < CT; ++ct) {
      float bv = bias[ct * 16 + cb];
#pragma unroll
      for (int r = 0; r < 4; ++r) {
        int row = rbase + r;
        if (row < N_) {
          float g = gelu_f(acc[ct][r] + bv);
          if constexpr (EPI == 2) g *= mulf[(long)row * C + ct * 16 + cb];
          out[(long)row * C + ct * 16 + cb] = f2b(g);
        }
      }
    }
  } else if constexpr (EPI == 4) {
    float* out = (float*)outv;
#pragma unroll
    for (int r = 0; r < 4; ++r) {
      int row = rbase + r;
      float xv[CT];
      float ss = 0.f;
#pragma unroll
      for (int ct = 0; ct < CT; ++ct) {
        float x = acc[ct][r] + bias[ct * 16 + cb];
        x = x > 0.f ? x : 0.01f * x;
        xv[ct] = x; ss += x * x;
      }
#pragma unroll
      for (int o = 1; o < 16; o <<= 1) ss += __shfl_xor(ss, o);
      float inv = 1.f / fmaxf(sqrtf(ss), 1e-12f);
      if (row < N_)
#pragma unroll
        for (int ct = 0; ct < CT; ++ct) out[(long)row * C + ct * 16 + cb] = xv[ct] * inv;
    }
  } else {   // EPI == 5: dual mask, two N x 128 outputs
#pragma unroll
    for (int ct = 0; ct < CT; ++ct) {
      const bool lo = ct < 8;
      u16* op = lo ? (u16*)outv : (u16*)outv2;
      const int cc = (ct & 7) * 16 + cb;
      float bv = lo ? bias[cc] : bias2[cc];
#pragma unroll
      for (int r = 0; r < 4; ++r) {
        int row = rbase + r;
        if (row < N_) {
          float x = acc[ct][r] + bv;
          float fv = b2f(mulb[(long)row * 128 + cc]);
          op[(long)row * 128 + cc] = f2b(fv * sigmoid_f(x));
        }
      }
    }
  }
}

// ================= SAGE gather (ushort2/lane, /deg fused) =================
__global__ __launch_bounds__(256) void gather_bf128(const u16* __restrict__ h,
    const int* __restrict__ rowptr, const int* __restrict__ colsrc,
    u16* __restrict__ out) {
  int node = blockIdx.x * 4 + (threadIdx.x >> 6);
  int lane = threadIdx.x & 63;
  if (node >= N_) return;
  int beg = rowptr[node], end = rowptr[node + 1];
  float inv = 1.f / fmaxf((float)(end - beg), 1.f);
  float a0 = 0.f, a1 = 0.f;
  for (int j = beg; j < end; ++j) {
    int s = colsrc[j];
    u32 v = *(const u32*)(h + (long)s * 128 + 2 * lane);
    a0 += b2f((u16)(v & 0xffffu));
    a1 += b2f((u16)(v >> 16));
  }
  u32 r = (u32)f2b(a0 * inv) | ((u32)f2b(a1 * inv) << 16);
  *(u32*)(out + (long)node * 128 + 2 * lane) = r;
}

// K=64: two edges per wave iteration
__global__ __launch_bounds__(256) void gather_bf64(const u16* __restrict__ h,
    const int* __restrict__ rowptr, const int* __restrict__ colsrc,
    u16* __restrict__ out) {
  int node = blockIdx.x * 4 + (threadIdx.x >> 6);
  int lane = threadIdx.x & 63;
  if (node >= N_) return;
  int beg = rowptr[node], end = rowptr[node + 1];
  int half = lane >> 5, cl = lane & 31;
  float a0 = 0.f, a1 = 0.f;
  for (int j = beg + half; j < end; j += 2) {
    int s = colsrc[j];
    u32 v = *(const u32*)(h + (long)s * 64 + 2 * cl);
    a0 += b2f((u16)(v & 0xffffu));
    a1 += b2f((u16)(v >> 16));
  }
  a0 += __shfl_xor(a0, 32);
  a1 += __shfl_xor(a1, 32);
  if (lane < 32) {
    float inv = 1.f / fmaxf((float)(end - beg), 1.f);
    u32 r = (u32)f2b(a0 * inv) | ((u32)f2b(a1 * inv) << 16);
    *(u32*)(out + (long)node * 64 + 2 * lane) = r;
  }
}

// ================= fused GATv2 =================
// split-lane layout: lane l owns cols {2l,2l+1}; lanes 0-31 = head0, 32-63 = head1.
// raw exp (logits bounded); 2x-unrolled edge loop for shuffle-chain ILP.
template <bool LAYER1>
__global__ __launch_bounds__(256) void gat_fused(const u16* __restrict__ fsfd,
    const int* __restrict__ rowptr, const int* __restrict__ colsrc,
    const float* __restrict__ attn, const float* __restrict__ bias,
    const float* __restrict__ drop, void* __restrict__ outv) {
  int node = blockIdx.x * 4 + (threadIdx.x >> 6);
  int lane = threadIdx.x & 63;
  if (node >= N_) return;
  float2 av = *(const float2*)(attn + 2 * lane);
  u32 fdv = *(const u32*)(fsfd + (long)node * 256 + 128 + 2 * lane);
  float fd0 = b2f((u16)(fdv & 0xffffu)), fd1 = b2f((u16)(fdv >> 16));
  float d_own = 0.f, acc0 = 0.f, acc1 = 0.f;
  const int beg = rowptr[node], end = rowptr[node + 1];
  int j = beg;
  for (; j + 2 <= end; j += 2) {
    int s0 = colsrc[j], s1 = colsrc[j + 1];
    u32 v0 = *(const u32*)(fsfd + (long)s0 * 256 + 2 * lane);
    u32 v1 = *(const u32*)(fsfd + (long)s1 * 256 + 2 * lane);
    float f00 = b2f((u16)(v0 & 0xffffu)), f01 = b2f((u16)(v0 >> 16));
    float f10 = b2f((u16)(v1 & 0xffffu)), f11 = b2f((u16)(v1 >> 16));
    float x00 = f00 + fd0; x00 = x00 > 0.f ? x00 : 0.2f * x00;
    float x01 = f01 + fd1; x01 = x01 > 0.f ? x01 : 0.2f * x01;
    float x10 = f10 + fd0; x10 = x10 > 0.f ? x10 : 0.2f * x10;
    float x11 = f11 + fd1; x11 = x11 > 0.f ? x11 : 0.2f * x11;
    float c0 = x00 * av.x + x01 * av.y;
    float c1 = x10 * av.x + x11 * av.y;
#pragma unroll
    for (int o = 16; o; o >>= 1) { c0 += __shfl_xor(c0, o); c1 += __shfl_xor(c1, o); }
    float e0 = __expf(c0), e1 = __expf(c1);
    d_own += e0 + e1;
    acc0 += e0 * f00 + e1 * f10;
    acc1 += e0 * f01 + e1 * f11;
  }
  if (j < end) {
    int s = colsrc[j];
    u32 fv = *(const u32*)(fsfd + (long)s * 256 + 2 * lane);
    float f0 = b2f((u16)(fv & 0xffffu)), f1 = b2f((u16)(fv >> 16));
    float x0 = f0 + fd0; x0 = x0 > 0.f ? x0 : 0.2f * x0;
    float x1 = f1 + fd1; x1 = x1 > 0.f ? x1 : 0.2f * x1;
    float c = x0 * av.x + x1 * av.y;
#pragma unroll
    for (int o = 16; o; o >>= 1) c += __shfl_xor(c, o);
    float e = __expf(c);
    d_own += e;
    acc0 += e * f0;
    acc1 += e * f1;
  }
  float2 bv = *(const float2*)(bias + 2 * lane);
  float inv = d_own > 0.f ? 1.f / d_own : 0.f;
  float g0 = gelu_f(bv.x + acc0 * inv);
  float g1 = gelu_f(bv.y + acc1 * inv);
  float v0 = 0.5f * (g0 + __shfl_xor(g0, 32));
  float v1 = 0.5f * (g1 + __shfl_xor(g1, 32));
  if constexpr (LAYER1) {
    if (lane < 32) {
      float2 dv = *(const float2*)(drop + (long)node * 64 + 2 * lane);
      u32 r = (u32)f2b(v0 * dv.x) | ((u32)f2b(v1 * dv.y) << 16);
      *(u32*)((u16*)outv + (long)node * 64 + 2 * lane) = r;
    }
  } else {
    float ss = v0 * v0 + v1 * v1;
#pragma unroll
    for (int o = 16; o; o >>= 1) ss += __shfl_xor(ss, o);
    float sc = 1.f / fmaxf(sqrtf(ss), 1e-12f);
    if (lane < 32) {
      float2 r; r.x = v0 * sc; r.y = v1 * sc;
      *(float2*)((float*)outv + (long)node * 64 + 2 * lane) = r;
    }
  }
}

extern "C" void kernel_launch(void* const* d_in, const int* in_sizes, int n_in,
                              void* d_out, int out_size, void* d_ws, size_t ws_size,
                              hipStream_t stream) {
  const float* feat = (const float*)d_in[0];
  const int*   esrc = (const int*)d_in[1];
  const int*   edst = (const int*)d_in[2];
  const float* Wmt = (const float*)d_in[3],  *bmt = (const float*)d_in[4];
  const float* Wms = (const float*)d_in[5],  *bms = (const float*)d_in[6];
  const float* W1s = (const float*)d_in[7],  *W1n = (const float*)d_in[8],  *b1 = (const float*)d_in[9];
  const float* W2s = (const float*)d_in[10], *W2n = (const float*)d_in[11], *b2 = (const float*)d_in[12];
  const float* g1Ws = (const float*)d_in[13], *g1Wd = (const float*)d_in[14];
  const float* g1a  = (const float*)d_in[15], *g1b  = (const float*)d_in[16];
  const float* g2Ws = (const float*)d_in[17], *g2Wd = (const float*)d_in[18];
  const float* g2a  = (const float*)d_in[19], *g2b  = (const float*)d_in[20];
  const float* W3  = (const float*)d_in[21], *b3 = (const float*)d_in[22];
  const float* dropt = (const float*)d_in[23], *drops = (const float*)d_in[24];

  float* out_t = (float*)d_out;
  float* out_s = out_t + (long)N_ * 64;

  // workspace (u16 units)
  u16* wsh = (u16*)d_ws;
  u16* featbf = wsh;                 // N*128
  u16* hbuf_t = wsh +  6400000;      // N*128
  u16* hbuf_s = wsh + 12800000;      // N*128
  u16* hn     = wsh + 19200000;      // N*128
  u16* h1     = wsh + 25600000;      // N*64
  u16* hn2    = wsh + 28800000;      // N*64
  u16* h2     = wsh + 32000000;      // N*64
  u16* hs1    = wsh + 35200000;      // N*64
  u16* fsfd   = wsh + 38400000;      // N*256
  u16* Wpk    = wsh + 51200000;      // 118784
  int* degi   = (int*)(wsh + 51318784);  // N
  int* cursor = degi + N_;               // N
  int* rowptr = cursor + N_;             // N+1
  int* colsrc = rowptr + N_ + 1;         // E
  int* bsum   = colsrc + E_;             // NB_
  int* bpre   = bsum + NB_;              // NB_+1

  const u16* WpMT = Wpk;             // [Wmt|Wms] fused: CT=16 reads both
  const u16* WpS1 = Wpk + 32768;
  const u16* WpS2 = Wpk + 49152;
  const u16* WpG1 = Wpk + 57344;
  const u16* WpG2 = Wpk + 90112;
  const u16* WpW3 = Wpk + 106496;

  constexpr int GB = (N_ + 63) / 64;

  // ---- CSR + packing ----
  hipMemsetAsync(degi, 0, (size_t)(2 * N_) * sizeof(int), stream);   // degi + cursor
  deg_int_kernel<<<(E_ + 255) / 256, 256, 0, stream>>>(edst, degi);
  scan_local<<<NB_, 256, 0, stream>>>(degi, rowptr, bsum);
  scan_block<<<1, 256, 0, stream>>>(bsum, bpre);
  scan_add<<<(N_ + 256) / 256, 256, 0, stream>>>(rowptr, bpre);
  csr_fill<<<(E_ + 255) / 256, 256, 0, stream>>>(esrc, edst, rowptr, cursor, colsrc);
  pack_feat<<<N_ * 128 / 4 / 256, 256, 0, stream>>>(feat, featbf);
  pack_w<<<464, 256, 0, stream>>>(Wmt, Wms, W1s, W1n, W2s, W2n,
                                  g1Ws, g1Wd, g2Ws, g2Wd, W3, Wpk);

  // ---- both feature masks in one GEMM ----
  gemm_mfma<128, 0, 256, 5><<<GB, 256, 0, stream>>>(featbf, nullptr, WpMT, bmt, bms,
                                                    featbf, nullptr, hbuf_t, hbuf_s);

  // ---- topology branch (SAGE) ----
  gather_bf128<<<N_ / 4, 256, 0, stream>>>(hbuf_t, rowptr, colsrc, hn);
  gemm_mfma<128, 128, 64, 2><<<GB, 256, 0, stream>>>(hbuf_t, hn, WpS1, b1, nullptr,
                                                     nullptr, dropt, h1, nullptr);
  gather_bf64<<<N_ / 4, 256, 0, stream>>>(h1, rowptr, colsrc, hn2);
  gemm_mfma<64, 64, 64, 3><<<GB, 256, 0, stream>>>(h1, hn2, WpS2, b2, nullptr,
                                                   nullptr, nullptr, h2, nullptr);
  gemm_mfma<64, 128, 64, 4><<<GB, 256, 0, stream>>>(h2, featbf, WpW3, b3, nullptr,
                                                    nullptr, nullptr, out_t, nullptr);

  // ---- semantic branch (GATv2) ----
  gemm_mfma<128, 0, 256, 0><<<GB, 256, 0, stream>>>(hbuf_s, nullptr, WpG1, nullptr, nullptr,
                                                    nullptr, nullptr, fsfd, nullptr);
  gat_fused<true><<<N_ / 4, 256, 0, stream>>>(fsfd, rowptr, colsrc, g1a, g1b, drops, hs1);
  gemm_mfma<64, 0, 256, 0><<<GB, 256, 0, stream>>>(hs1, nullptr, WpG2, nullptr, nullptr,
                                                   nullptr, nullptr, fsfd, nullptr);
  gat_fused<false><<<N_ / 4, 256, 0, stream>>>(fsfd, rowptr, colsrc, g2a, g2b, nullptr, out_s);
}

// Round 6
// 356.560 us; speedup vs baseline: 6.9360x; 1.0858x over previous
//
#include <hip/hip_runtime.h>
#include <math.h>

constexpr int N_  = 50000;
constexpr int E_  = 500000;
constexpr int NB_ = (N_ + 255) / 256;   // 196 scan blocks

typedef unsigned short u16;
typedef unsigned int u32;
typedef short short8 __attribute__((ext_vector_type(8)));
typedef __bf16 bf16x8 __attribute__((ext_vector_type(8)));
typedef float f32x4 __attribute__((ext_vector_type(4)));
typedef short short4v __attribute__((ext_vector_type(4)));

#define DINL __device__ __forceinline__

DINL float gelu_f(float x) { return 0.5f * x * (1.f + erff(x * 0.70710678118654752f)); }
DINL float sigmoid_f(float x) { return 1.f / (1.f + expf(-x)); }
DINL u16 f2b(float x) {            // f32 -> bf16 RNE
  unsigned u = __float_as_uint(x);
  return (u16)((u + 0x7FFFu + ((u >> 16) & 1u)) >> 16);
}
DINL float b2f(u16 b) { return __uint_as_float(((unsigned)b) << 16); }

// ================= CSR build =================
__global__ void deg_int_kernel(const int* __restrict__ dst, int* __restrict__ deg) {
  int t = blockIdx.x * 256 + threadIdx.x;
  if (t < E_) atomicAdd(&deg[dst[t]], 1);
}

__global__ __launch_bounds__(256) void scan_local(const int* __restrict__ deg,
    int* __restrict__ rowptr, int* __restrict__ bsum) {
  __shared__ int sums[4];
  const int tid = threadIdx.x, lane = tid & 63, wid = tid >> 6;
  const int i = blockIdx.x * 256 + tid;
  int v = (i < N_) ? deg[i] : 0;
  int x = v;
#pragma unroll
  for (int o = 1; o < 64; o <<= 1) { int y = __shfl_up(x, o); if (lane >= o) x += y; }
  if (lane == 63) sums[wid] = x;
  __syncthreads();
  int woff = 0;
#pragma unroll
  for (int w = 0; w < 3; ++w) if (w < wid) woff += sums[w];
  if (i < N_) rowptr[i] = x - v + woff;
  if (tid == 255) bsum[blockIdx.x] = woff + x;
}

__global__ __launch_bounds__(256) void scan_block(const int* __restrict__ bsum,
                                                  int* __restrict__ bpre) {
  __shared__ int sums[4];
  const int tid = threadIdx.x, lane = tid & 63, wid = tid >> 6;
  int v = (tid < NB_) ? bsum[tid] : 0;
  int x = v;
#pragma unroll
  for (int o = 1; o < 64; o <<= 1) { int y = __shfl_up(x, o); if (lane >= o) x += y; }
  if (lane == 63) sums[wid] = x;
  __syncthreads();
  int woff = 0;
#pragma unroll
  for (int w = 0; w < 3; ++w) if (w < wid) woff += sums[w];
  if (tid < NB_) bpre[tid] = x - v + woff;
  if (tid == 255) bpre[NB_] = woff + x;
}

__global__ __launch_bounds__(256) void scan_add(int* __restrict__ rowptr,
                                                const int* __restrict__ bpre) {
  int i = blockIdx.x * 256 + threadIdx.x;
  if (i < N_) rowptr[i] += bpre[i >> 8];
  else if (i == N_) rowptr[N_] = bpre[NB_];
}

__global__ void csr_fill(const int* __restrict__ src, const int* __restrict__ dst,
                         const int* __restrict__ rowptr, int* __restrict__ cursor,
                         int* __restrict__ colsrc) {
  int e = blockIdx.x * 256 + threadIdx.x;
  if (e >= E_) return;
  int d = dst[e];
  int pos = rowptr[d] + atomicAdd(&cursor[d], 1);
  colsrc[pos] = src[e];
}

// ================= packing =================
__global__ __launch_bounds__(256) void pack_feat(const float* __restrict__ f,
                                                 u16* __restrict__ o) {
  int t = blockIdx.x * 256 + threadIdx.x;
  float4 v = ((const float4*)f)[t];
  short4v r;
  r[0] = (short)f2b(v.x); r[1] = (short)f2b(v.y);
  r[2] = (short)f2b(v.z); r[3] = (short)f2b(v.w);
  ((short4v*)o)[t] = r;
}

// pack weights into MFMA B-fragment order:
// dst[((ct*(K/32)+ks)*64+lane)*8+j] = W[ks*32+(lane>>4)*8+j][ct*16+(lane&15)]
__global__ __launch_bounds__(256) void pack_w(
    const float* __restrict__ Wmt, const float* __restrict__ Wms,
    const float* __restrict__ W1s, const float* __restrict__ W1n,
    const float* __restrict__ W2s, const float* __restrict__ W2n,
    const float* __restrict__ g1Ws, const float* __restrict__ g1Wd,
    const float* __restrict__ g2Ws, const float* __restrict__ g2Wd,
    const float* __restrict__ W3, u16* __restrict__ dst) {
  int e = blockIdx.x * 256 + threadIdx.x;
  const float *Wa, *Wb = nullptr;
  int K1, K2 = 0, Ca, Cb = 0, st;
  if (e < 16384)       { Wa = Wmt;  K1 = 128; Ca = 128;           st = 0; }
  else if (e < 32768)  { Wa = Wms;  K1 = 128; Ca = 128;           st = 16384; }
  else if (e < 49152)  { Wa = W1s;  Wb = W1n; K1 = 128; K2 = 128; Ca = 64;  st = 32768; }
  else if (e < 57344)  { Wa = W2s;  Wb = W2n; K1 = 64;  K2 = 64;  Ca = 64;  st = 49152; }
  else if (e < 90112)  { Wa = g1Ws; Wb = g1Wd; K1 = 128; Ca = 128; Cb = 128; st = 57344; }
  else if (e < 106496) { Wa = g2Ws; Wb = g2Wd; K1 = 64;  Ca = 128; Cb = 128; st = 90112; }
  else                 { Wa = W3;   K1 = 192; Ca = 64;            st = 106496; }
  int el = e - st;
  int Kt = K1 + K2;
  int ct = el / (Kt * 16);
  int rem = el - ct * Kt * 16;
  int ks = rem >> 9, rem2 = rem & 511, lane = rem2 >> 3, j = rem2 & 7;
  int k = ks * 32 + ((lane >> 4) << 3) + j;
  int c = ct * 16 + (lane & 15);
  float v;
  if (k < K1) v = (c < Ca) ? Wa[k * Ca + c] : Wb[k * Cb + (c - Ca)];
  else        v = Wb[(k - K1) * Ca + c];
  dst[e] = f2b(v);
}

// ================= MFMA GEMM (wave-split columns, B in registers) =================
// block = 64 rows x C cols, 4 waves; wave w owns column quadrant [w*C/4, (w+1)*C/4)
// and iterates all 4 row-groups from LDS. B fragments preloaded to VGPRs.
// EPI: 0 plain bf16, 2 gelu*drop, 3 gelu, 4 leaky+l2norm(f32),
//      5 dual-mask: waves 0-1 -> outv (bias), waves 2-3 -> outv2 (bias2)
template <int K1, int K2, int C, int EPI>
__global__ __launch_bounds__(256) void gemm_mfma(
    const u16* __restrict__ A1, const u16* __restrict__ A2,
    const u16* __restrict__ Wp, const float* __restrict__ bias,
    const float* __restrict__ bias2, const u16* __restrict__ mulb,
    const float* __restrict__ mulf, void* __restrict__ outv,
    void* __restrict__ outv2) {
  constexpr int K = K1 + K2, SK = K + 8, KS = K / 32, CT4 = C / 64;
  __shared__ u16 alds[64 * SK];
  const int tid = threadIdx.x;
  const int w = tid >> 6, l = tid & 63;
  const int wr0 = blockIdx.x * 64;

  // preload B fragments for this wave's column quadrant (overlaps staging)
  short8 bfrag[KS][CT4];
#pragma unroll
  for (int ks = 0; ks < KS; ++ks)
#pragma unroll
    for (int c4 = 0; c4 < CT4; ++c4)
      bfrag[ks][c4] = *(const short8*)(Wp +
          ((size_t)((w * CT4 + c4) * KS + ks) * 64 + l) * 8);

  // stage A into LDS
  for (int i = tid; i < 64 * (K1 / 8); i += 256) {
    int rr = i / (K1 / 8), kc = i % (K1 / 8);
    int gr = wr0 + rr; if (gr >= N_) gr = N_ - 1;
    short8 v = *(const short8*)(A1 + (long)gr * K1 + kc * 8);
    *(short8*)&alds[rr * SK + kc * 8] = v;
  }
  if constexpr (K2 > 0) {
    for (int i = tid; i < 64 * (K2 / 8); i += 256) {
      int rr = i / (K2 / 8), kc = i % (K2 / 8);
      int gr = wr0 + rr; if (gr >= N_) gr = N_ - 1;
      short8 v = *(const short8*)(A2 + (long)gr * K2 + kc * 8);
      *(short8*)&alds[rr * SK + K1 + kc * 8] = v;
    }
  }
  __syncthreads();

  f32x4 acc[4][CT4];
#pragma unroll
  for (int rg = 0; rg < 4; ++rg)
#pragma unroll
    for (int c4 = 0; c4 < CT4; ++c4) acc[rg][c4] = (f32x4){0.f, 0.f, 0.f, 0.f};

#pragma unroll
  for (int ks = 0; ks < KS; ++ks) {
#pragma unroll
    for (int rg = 0; rg < 4; ++rg) {
      short8 av = *(const short8*)&alds[(rg * 16 + (l & 15)) * SK + ks * 32 + ((l >> 4) << 3)];
      bf16x8 af = __builtin_bit_cast(bf16x8, av);
#pragma unroll
      for (int c4 = 0; c4 < CT4; ++c4)
        acc[rg][c4] = __builtin_amdgcn_mfma_f32_16x16x32_bf16(
            af, __builtin_bit_cast(bf16x8, bfrag[ks][c4]), acc[rg][c4], 0, 0, 0);
    }
  }

  const int cb = l & 15;
  const int rsub = (l >> 4) << 2;           // row offset within 16-row group
  if constexpr (EPI == 0) {
    u16* out = (u16*)outv;
#pragma unroll
    for (int rg = 0; rg < 4; ++rg)
#pragma unroll
      for (int c4 = 0; c4 < CT4; ++c4) {
        int col = (w * CT4 + c4) * 16 + cb;
#pragma unroll
        for (int r = 0; r < 4; ++r) {
          int row = wr0 + rg * 16 + rsub + r;
          if (row < N_) out[(long)row * C + col] = f2b(acc[rg][c4][r]);
        }
      }
  } else if constexpr (EPI == 2 || EPI == 3) {
    u16* out = (u16*)outv;
#pragma unroll
    for (int rg = 0; rg < 4; ++rg)
#pragma unroll
      for (int c4 = 0; c4 < CT4; ++c4) {
        int col = (w * CT4 + c4) * 16 + cb;
        float bv = bias[col];
#pragma unroll
        for (int r = 0; r < 4; ++r) {
          int row = wr0 + rg * 16 + rsub + r;
          if (row < N_) {
            float g = gelu_f(acc[rg][c4][r] + bv);
            if constexpr (EPI == 2) g *= mulf[(long)row * C + col];
            out[(long)row * C + col] = f2b(g);
          }
        }
      }
  } else if constexpr (EPI == 4) {          // C=64, CT4=1: leaky + row l2norm
    __shared__ float ssb[64][4];
    float* out = (float*)outv;
    const int col = w * 16 + cb;
    const float bv = bias[col];
    float xv[4][4];
#pragma unroll
    for (int rg = 0; rg < 4; ++rg)
#pragma unroll
      for (int r = 0; r < 4; ++r) {
        float x = acc[rg][0][r] + bv;
        x = x > 0.f ? x : 0.01f * x;
        xv[rg][r] = x;
        float ss = x * x;
#pragma unroll
        for (int o = 1; o < 16; o <<= 1) ss += __shfl_xor(ss, o);
        if (cb == 0) ssb[rg * 16 + rsub + r][w] = ss;
      }
    __syncthreads();
#pragma unroll
    for (int rg = 0; rg < 4; ++rg)
#pragma unroll
      for (int r = 0; r < 4; ++r) {
        int lrow = rg * 16 + rsub + r;
        float ss = ssb[lrow][0] + ssb[lrow][1] + ssb[lrow][2] + ssb[lrow][3];
        float sc = 1.f / fmaxf(sqrtf(ss), 1e-12f);
        int row = wr0 + lrow;
        if (row < N_) out[(long)row * 64 + col] = xv[rg][r] * sc;
      }
  } else {                                  // EPI == 5: dual mask (C=256)
#pragma unroll
    for (int c4 = 0; c4 < CT4; ++c4) {
      const int ct = w * CT4 + c4;
      const bool lo = ct < 8;
      u16* op = lo ? (u16*)outv : (u16*)outv2;
      const int cc = (ct & 7) * 16 + cb;
      float bv = lo ? bias[cc] : bias2[cc];
#pragma unroll
      for (int rg = 0; rg < 4; ++rg)
#pragma unroll
        for (int r = 0; r < 4; ++r) {
          int row = wr0 + rg * 16 + rsub + r;
          if (row < N_) {
            float x = acc[rg][c4][r] + bv;
            float fv = b2f(mulb[(long)row * 128 + cc]);
            op[(long)row * 128 + cc] = f2b(fv * sigmoid_f(x));
          }
        }
    }
  }
}

// ================= SAGE gather (ushort2/lane, /deg fused) =================
__global__ __launch_bounds__(256) void gather_bf128(const u16* __restrict__ h,
    const int* __restrict__ rowptr, const int* __restrict__ colsrc,
    u16* __restrict__ out) {
  int node = blockIdx.x * 4 + (threadIdx.x >> 6);
  int lane = threadIdx.x & 63;
  if (node >= N_) return;
  int beg = rowptr[node], end = rowptr[node + 1];
  float inv = 1.f / fmaxf((float)(end - beg), 1.f);
  float a0 = 0.f, a1 = 0.f;
  for (int j = beg; j < end; ++j) {
    int s = colsrc[j];
    u32 v = *(const u32*)(h + (long)s * 128 + 2 * lane);
    a0 += b2f((u16)(v & 0xffffu));
    a1 += b2f((u16)(v >> 16));
  }
  u32 r = (u32)f2b(a0 * inv) | ((u32)f2b(a1 * inv) << 16);
  *(u32*)(out + (long)node * 128 + 2 * lane) = r;
}

__global__ __launch_bounds__(256) void gather_bf64(const u16* __restrict__ h,
    const int* __restrict__ rowptr, const int* __restrict__ colsrc,
    u16* __restrict__ out) {
  int node = blockIdx.x * 4 + (threadIdx.x >> 6);
  int lane = threadIdx.x & 63;
  if (node >= N_) return;
  int beg = rowptr[node], end = rowptr[node + 1];
  int half = lane >> 5, cl = lane & 31;
  float a0 = 0.f, a1 = 0.f;
  for (int j = beg + half; j < end; j += 2) {
    int s = colsrc[j];
    u32 v = *(const u32*)(h + (long)s * 64 + 2 * cl);
    a0 += b2f((u16)(v & 0xffffu));
    a1 += b2f((u16)(v >> 16));
  }
  a0 += __shfl_xor(a0, 32);
  a1 += __shfl_xor(a1, 32);
  if (lane < 32) {
    float inv = 1.f / fmaxf((float)(end - beg), 1.f);
    u32 r = (u32)f2b(a0 * inv) | ((u32)f2b(a1 * inv) << 16);
    *(u32*)(out + (long)node * 64 + 2 * lane) = r;
  }
}

// ================= fused GATv2 =================
template <bool LAYER1>
__global__ __launch_bounds__(256) void gat_fused(const u16* __restrict__ fsfd,
    const int* __restrict__ rowptr, const int* __restrict__ colsrc,
    const float* __restrict__ attn, const float* __restrict__ bias,
    const float* __restrict__ drop, void* __restrict__ outv) {
  int node = blockIdx.x * 4 + (threadIdx.x >> 6);
  int lane = threadIdx.x & 63;
  if (node >= N_) return;
  float2 av = *(const float2*)(attn + 2 * lane);
  u32 fdv = *(const u32*)(fsfd + (long)node * 256 + 128 + 2 * lane);
  float fd0 = b2f((u16)(fdv & 0xffffu)), fd1 = b2f((u16)(fdv >> 16));
  float d_own = 0.f, acc0 = 0.f, acc1 = 0.f;
  const int beg = rowptr[node], end = rowptr[node + 1];
  int j = beg;
  for (; j + 2 <= end; j += 2) {
    int s0 = colsrc[j], s1 = colsrc[j + 1];
    u32 v0 = *(const u32*)(fsfd + (long)s0 * 256 + 2 * lane);
    u32 v1 = *(const u32*)(fsfd + (long)s1 * 256 + 2 * lane);
    float f00 = b2f((u16)(v0 & 0xffffu)), f01 = b2f((u16)(v0 >> 16));
    float f10 = b2f((u16)(v1 & 0xffffu)), f11 = b2f((u16)(v1 >> 16));
    float x00 = f00 + fd0; x00 = x00 > 0.f ? x00 : 0.2f * x00;
    float x01 = f01 + fd1; x01 = x01 > 0.f ? x01 : 0.2f * x01;
    float x10 = f10 + fd0; x10 = x10 > 0.f ? x10 : 0.2f * x10;
    float x11 = f11 + fd1; x11 = x11 > 0.f ? x11 : 0.2f * x11;
    float c0 = x00 * av.x + x01 * av.y;
    float c1 = x10 * av.x + x11 * av.y;
#pragma unroll
    for (int o = 16; o; o >>= 1) { c0 += __shfl_xor(c0, o); c1 += __shfl_xor(c1, o); }
    float e0 = __expf(c0), e1 = __expf(c1);
    d_own += e0 + e1;
    acc0 += e0 * f00 + e1 * f10;
    acc1 += e0 * f01 + e1 * f11;
  }
  if (j < end) {
    int s = colsrc[j];
    u32 fv = *(const u32*)(fsfd + (long)s * 256 + 2 * lane);
    float f0 = b2f((u16)(fv & 0xffffu)), f1 = b2f((u16)(fv >> 16));
    float x0 = f0 + fd0; x0 = x0 > 0.f ? x0 : 0.2f * x0;
    float x1 = f1 + fd1; x1 = x1 > 0.f ? x1 : 0.2f * x1;
    float c = x0 * av.x + x1 * av.y;
#pragma unroll
    for (int o = 16; o; o >>= 1) c += __shfl_xor(c, o);
    float e = __expf(c);
    d_own += e;
    acc0 += e * f0;
    acc1 += e * f1;
  }
  float2 bv = *(const float2*)(bias + 2 * lane);
  float inv = d_own > 0.f ? 1.f / d_own : 0.f;
  float g0 = gelu_f(bv.x + acc0 * inv);
  float g1 = gelu_f(bv.y + acc1 * inv);
  float v0 = 0.5f * (g0 + __shfl_xor(g0, 32));
  float v1 = 0.5f * (g1 + __shfl_xor(g1, 32));
  if constexpr (LAYER1) {
    if (lane < 32) {
      float2 dv = *(const float2*)(drop + (long)node * 64 + 2 * lane);
      u32 r = (u32)f2b(v0 * dv.x) | ((u32)f2b(v1 * dv.y) << 16);
      *(u32*)((u16*)outv + (long)node * 64 + 2 * lane) = r;
    }
  } else {
    float ss = v0 * v0 + v1 * v1;
#pragma unroll
    for (int o = 16; o; o >>= 1) ss += __shfl_xor(ss, o);
    float sc = 1.f / fmaxf(sqrtf(ss), 1e-12f);
    if (lane < 32) {
      float2 r; r.x = v0 * sc; r.y = v1 * sc;
      *(float2*)((float*)outv + (long)node * 64 + 2 * lane) = r;
    }
  }
}

extern "C" void kernel_launch(void* const* d_in, const int* in_sizes, int n_in,
                              void* d_out, int out_size, void* d_ws, size_t ws_size,
                              hipStream_t stream) {
  const float* feat = (const float*)d_in[0];
  const int*   esrc = (const int*)d_in[1];
  const int*   edst = (const int*)d_in[2];
  const float* Wmt = (const float*)d_in[3],  *bmt = (const float*)d_in[4];
  const float* Wms = (const float*)d_in[5],  *bms = (const float*)d_in[6];
  const float* W1s = (const float*)d_in[7],  *W1n = (const float*)d_in[8],  *b1 = (const float*)d_in[9];
  const float* W2s = (const float*)d_in[10], *W2n = (const float*)d_in[11], *b2 = (const float*)d_in[12];
  const float* g1Ws = (const float*)d_in[13], *g1Wd = (const float*)d_in[14];
  const float* g1a  = (const float*)d_in[15], *g1b  = (const float*)d_in[16];
  const float* g2Ws = (const float*)d_in[17], *g2Wd = (const float*)d_in[18];
  const float* g2a  = (const float*)d_in[19], *g2b  = (const float*)d_in[20];
  const float* W3  = (const float*)d_in[21], *b3 = (const float*)d_in[22];
  const float* dropt = (const float*)d_in[23], *drops = (const float*)d_in[24];

  float* out_t = (float*)d_out;
  float* out_s = out_t + (long)N_ * 64;

  // workspace (u16 units)
  u16* wsh = (u16*)d_ws;
  u16* featbf = wsh;                 // N*128
  u16* hbuf_t = wsh +  6400000;      // N*128
  u16* hbuf_s = wsh + 12800000;      // N*128
  u16* hn     = wsh + 19200000;      // N*128
  u16* h1     = wsh + 25600000;      // N*64
  u16* hn2    = wsh + 28800000;      // N*64
  u16* h2     = wsh + 32000000;      // N*64
  u16* hs1    = wsh + 35200000;      // N*64
  u16* fsfd   = wsh + 38400000;      // N*256
  u16* Wpk    = wsh + 51200000;      // 118784
  int* degi   = (int*)(wsh + 51318784);  // N
  int* cursor = degi + N_;               // N
  int* rowptr = cursor + N_;             // N+1
  int* colsrc = rowptr + N_ + 1;         // E
  int* bsum   = colsrc + E_;             // NB_
  int* bpre   = bsum + NB_;              // NB_+1

  const u16* WpMT = Wpk;             // [Wmt|Wms] fused
  const u16* WpS1 = Wpk + 32768;
  const u16* WpS2 = Wpk + 49152;
  const u16* WpG1 = Wpk + 57344;
  const u16* WpG2 = Wpk + 90112;
  const u16* WpW3 = Wpk + 106496;

  constexpr int GB = (N_ + 63) / 64;

  // ---- CSR + packing ----
  hipMemsetAsync(degi, 0, (size_t)(2 * N_) * sizeof(int), stream);
  deg_int_kernel<<<(E_ + 255) / 256, 256, 0, stream>>>(edst, degi);
  scan_local<<<NB_, 256, 0, stream>>>(degi, rowptr, bsum);
  scan_block<<<1, 256, 0, stream>>>(bsum, bpre);
  scan_add<<<(N_ + 256) / 256, 256, 0, stream>>>(rowptr, bpre);
  csr_fill<<<(E_ + 255) / 256, 256, 0, stream>>>(esrc, edst, rowptr, cursor, colsrc);
  pack_feat<<<N_ * 128 / 4 / 256, 256, 0, stream>>>(feat, featbf);
  pack_w<<<464, 256, 0, stream>>>(Wmt, Wms, W1s, W1n, W2s, W2n,
                                  g1Ws, g1Wd, g2Ws, g2Wd, W3, Wpk);

  // ---- both feature masks in one GEMM ----
  gemm_mfma<128, 0, 256, 5><<<GB, 256, 0, stream>>>(featbf, nullptr, WpMT, bmt, bms,
                                                    featbf, nullptr, hbuf_t, hbuf_s);

  // ---- topology branch (SAGE) ----
  gather_bf128<<<N_ / 4, 256, 0, stream>>>(hbuf_t, rowptr, colsrc, hn);
  gemm_mfma<128, 128, 64, 2><<<GB, 256, 0, stream>>>(hbuf_t, hn, WpS1, b1, nullptr,
                                                     nullptr, dropt, h1, nullptr);
  gather_bf64<<<N_ / 4, 256, 0, stream>>>(h1, rowptr, colsrc, hn2);
  gemm_mfma<64, 64, 64, 3><<<GB, 256, 0, stream>>>(h1, hn2, WpS2, b2, nullptr,
                                                   nullptr, nullptr, h2, nullptr);
  gemm_mfma<64, 128, 64, 4><<<GB, 256, 0, stream>>>(h2, featbf, WpW3, b3, nullptr,
                                                    nullptr, nullptr, out_t, nullptr);

  // ---- semantic branch (GATv2) ----
  gemm_mfma<128, 0, 256, 0><<<GB, 256, 0, stream>>>(hbuf_s, nullptr, WpG1, nullptr, nullptr,
                                                    nullptr, nullptr, fsfd, nullptr);
  gat_fused<true><<<N_ / 4, 256, 0, stream>>>(fsfd, rowptr, colsrc, g1a, g1b, drops, hs1);
  gemm_mfma<64, 0, 256, 0><<<GB, 256, 0, stream>>>(hs1, nullptr, WpG2, nullptr, nullptr,
                                                   nullptr, nullptr, fsfd, nullptr);
  gat_fused<false><<<N_ / 4, 256, 0, stream>>>(fsfd, rowptr, colsrc, g2a, g2b, nullptr, out_s);
}

// Round 8
// 298.499 us; speedup vs baseline: 8.2851x; 1.1945x over previous
//
#include <hip/hip_runtime.h>
#include <math.h>

constexpr int N_  = 50000;
constexpr int E_  = 500000;
constexpr int NB_ = (N_ + 255) / 256;   // 196 scan blocks

typedef unsigned short u16;
typedef unsigned int u32;
typedef short short8 __attribute__((ext_vector_type(8)));
typedef __bf16 bf16x8 __attribute__((ext_vector_type(8)));
typedef float f32x4 __attribute__((ext_vector_type(4)));
typedef short short4v __attribute__((ext_vector_type(4)));

#define DINL __device__ __forceinline__

DINL float gelu_f(float x) { return 0.5f * x * (1.f + erff(x * 0.70710678118654752f)); }
DINL float sigmoid_f(float x) { return 1.f / (1.f + expf(-x)); }
DINL u16 f2b(float x) {            // f32 -> bf16 RNE
  unsigned u = __float_as_uint(x);
  return (u16)((u + 0x7FFFu + ((u >> 16) & 1u)) >> 16);
}
DINL float b2f(u16 b) { return __uint_as_float(((unsigned)b) << 16); }

// butterfly sum over each 32-lane half: 4 DPP stages (VALU pipe) + 1 ds_swizzle (xor16)
template <int CTRL>
DINL float dpp_add(float c) {
  int p = __builtin_amdgcn_update_dpp(0, __builtin_bit_cast(int, c), CTRL, 0xf, 0xf, false);
  return c + __builtin_bit_cast(float, p);
}
DINL float half_reduce(float c) {
  c = dpp_add<0xB1>(c);    // quad_perm [1,0,3,2]  : xor1
  c = dpp_add<0x4E>(c);    // quad_perm [2,3,0,1]  : xor2
  c = dpp_add<0x141>(c);   // row_half_mirror      : xor4
  c = dpp_add<0x140>(c);   // row_mirror           : xor8
  int p = __builtin_amdgcn_ds_swizzle(__builtin_bit_cast(int, c), 0x401F);  // xor16
  return c + __builtin_bit_cast(float, p);
}

// ================= CSR build =================
__global__ void deg_int_kernel(const int* __restrict__ dst, int* __restrict__ deg) {
  int t = blockIdx.x * 256 + threadIdx.x;
  if (t < E_) atomicAdd(&deg[dst[t]], 1);
}

__global__ __launch_bounds__(256) void scan_local(const int* __restrict__ deg,
    int* __restrict__ rowptr, int* __restrict__ bsum) {
  __shared__ int sums[4];
  const int tid = threadIdx.x, lane = tid & 63, wid = tid >> 6;
  const int i = blockIdx.x * 256 + tid;
  int v = (i < N_) ? deg[i] : 0;
  int x = v;
#pragma unroll
  for (int o = 1; o < 64; o <<= 1) { int y = __shfl_up(x, o); if (lane >= o) x += y; }
  if (lane == 63) sums[wid] = x;
  __syncthreads();
  int woff = 0;
#pragma unroll
  for (int w = 0; w < 3; ++w) if (w < wid) woff += sums[w];
  if (i < N_) rowptr[i] = x - v + woff;
  if (tid == 255) bsum[blockIdx.x] = woff + x;
}

__global__ __launch_bounds__(256) void scan_block(const int* __restrict__ bsum,
                                                  int* __restrict__ bpre) {
  __shared__ int sums[4];
  const int tid = threadIdx.x, lane = tid & 63, wid = tid >> 6;
  int v = (tid < NB_) ? bsum[tid] : 0;
  int x = v;
#pragma unroll
  for (int o = 1; o < 64; o <<= 1) { int y = __shfl_up(x, o); if (lane >= o) x += y; }
  if (lane == 63) sums[wid] = x;
  __syncthreads();
  int woff = 0;
#pragma unroll
  for (int w = 0; w < 3; ++w) if (w < wid) woff += sums[w];
  if (tid < NB_) bpre[tid] = x - v + woff;
  if (tid == 255) bpre[NB_] = woff + x;
}

__global__ __launch_bounds__(256) void scan_add(int* __restrict__ rowptr,
                                                const int* __restrict__ bpre) {
  int i = blockIdx.x * 256 + threadIdx.x;
  if (i < N_) rowptr[i] += bpre[i >> 8];
  else if (i == N_) rowptr[N_] = bpre[NB_];
}

__global__ void csr_fill(const int* __restrict__ src, const int* __restrict__ dst,
                         const int* __restrict__ rowptr, int* __restrict__ cursor,
                         int* __restrict__ colsrc) {
  int e = blockIdx.x * 256 + threadIdx.x;
  if (e >= E_) return;
  int d = dst[e];
  int pos = rowptr[d] + atomicAdd(&cursor[d], 1);
  colsrc[pos] = src[e];
}

// ================= packing =================
__global__ __launch_bounds__(256) void pack_feat(const float* __restrict__ f,
                                                 u16* __restrict__ o) {
  int t = blockIdx.x * 256 + threadIdx.x;
  float4 v = ((const float4*)f)[t];
  short4v r;
  r[0] = (short)f2b(v.x); r[1] = (short)f2b(v.y);
  r[2] = (short)f2b(v.z); r[3] = (short)f2b(v.w);
  ((short4v*)o)[t] = r;
}

// pack weights into MFMA B-fragment order:
// dst[((ct*(K/32)+ks)*64+lane)*8+j] = W[ks*32+(lane>>4)*8+j][ct*16+(lane&15)]
__global__ __launch_bounds__(256) void pack_w(
    const float* __restrict__ Wmt, const float* __restrict__ Wms,
    const float* __restrict__ W1s, const float* __restrict__ W1n,
    const float* __restrict__ W2s, const float* __restrict__ W2n,
    const float* __restrict__ g1Ws, const float* __restrict__ g1Wd,
    const float* __restrict__ g2Ws, const float* __restrict__ g2Wd,
    const float* __restrict__ W3, u16* __restrict__ dst) {
  int e = blockIdx.x * 256 + threadIdx.x;
  const float *Wa, *Wb = nullptr;
  int K1, K2 = 0, Ca, Cb = 0, st;
  if (e < 16384)       { Wa = Wmt;  K1 = 128; Ca = 128;           st = 0; }
  else if (e < 32768)  { Wa = Wms;  K1 = 128; Ca = 128;           st = 16384; }
  else if (e < 49152)  { Wa = W1s;  Wb = W1n; K1 = 128; K2 = 128; Ca = 64;  st = 32768; }
  else if (e < 57344)  { Wa = W2s;  Wb = W2n; K1 = 64;  K2 = 64;  Ca = 64;  st = 49152; }
  else if (e < 90112)  { Wa = g1Ws; Wb = g1Wd; K1 = 128; Ca = 128; Cb = 128; st = 57344; }
  else if (e < 106496) { Wa = g2Ws; Wb = g2Wd; K1 = 64;  Ca = 128; Cb = 128; st = 90112; }
  else                 { Wa = W3;   K1 = 192; Ca = 64;            st = 106496; }
  int el = e - st;
  int Kt = K1 + K2;
  int ct = el / (Kt * 16);
  int rem = el - ct * Kt * 16;
  int ks = rem >> 9, rem2 = rem & 511, lane = rem2 >> 3, j = rem2 & 7;
  int k = ks * 32 + ((lane >> 4) << 3) + j;
  int c = ct * 16 + (lane & 15);
  float v;
  if (k < K1) v = (c < Ca) ? Wa[k * Ca + c] : Wb[k * Cb + (c - Ca)];
  else        v = Wb[(k - K1) * Ca + c];
  dst[e] = f2b(v);
}

// ================= MFMA GEMM (wave-split columns, B in registers) =================
template <int K1, int K2, int C, int EPI>
__global__ __launch_bounds__(256) void gemm_mfma(
    const u16* __restrict__ A1, const u16* __restrict__ A2,
    const u16* __restrict__ Wp, const float* __restrict__ bias,
    const float* __restrict__ bias2, const u16* __restrict__ mulb,
    const float* __restrict__ mulf, void* __restrict__ outv,
    void* __restrict__ outv2) {
  constexpr int K = K1 + K2, SK = K + 8, KS = K / 32, CT4 = C / 64;
  __shared__ u16 alds[64 * SK];
  const int tid = threadIdx.x;
  const int w = tid >> 6, l = tid & 63;
  const int wr0 = blockIdx.x * 64;

  short8 bfrag[KS][CT4];
#pragma unroll
  for (int ks = 0; ks < KS; ++ks)
#pragma unroll
    for (int c4 = 0; c4 < CT4; ++c4)
      bfrag[ks][c4] = *(const short8*)(Wp +
          ((size_t)((w * CT4 + c4) * KS + ks) * 64 + l) * 8);

  for (int i = tid; i < 64 * (K1 / 8); i += 256) {
    int rr = i / (K1 / 8), kc = i % (K1 / 8);
    int gr = wr0 + rr; if (gr >= N_) gr = N_ - 1;
    short8 v = *(const short8*)(A1 + (long)gr * K1 + kc * 8);
    *(short8*)&alds[rr * SK + kc * 8] = v;
  }
  if constexpr (K2 > 0) {
    for (int i = tid; i < 64 * (K2 / 8); i += 256) {
      int rr = i / (K2 / 8), kc = i % (K2 / 8);
      int gr = wr0 + rr; if (gr >= N_) gr = N_ - 1;
      short8 v = *(const short8*)(A2 + (long)gr * K2 + kc * 8);
      *(short8*)&alds[rr * SK + K1 + kc * 8] = v;
    }
  }
  __syncthreads();

  f32x4 acc[4][CT4];
#pragma unroll
  for (int rg = 0; rg < 4; ++rg)
#pragma unroll
    for (int c4 = 0; c4 < CT4; ++c4) acc[rg][c4] = (f32x4){0.f, 0.f, 0.f, 0.f};

#pragma unroll
  for (int ks = 0; ks < KS; ++ks) {
#pragma unroll
    for (int rg = 0; rg < 4; ++rg) {
      short8 av = *(const short8*)&alds[(rg * 16 + (l & 15)) * SK + ks * 32 + ((l >> 4) << 3)];
      bf16x8 af = __builtin_bit_cast(bf16x8, av);
#pragma unroll
      for (int c4 = 0; c4 < CT4; ++c4)
        acc[rg][c4] = __builtin_amdgcn_mfma_f32_16x16x32_bf16(
            af, __builtin_bit_cast(bf16x8, bfrag[ks][c4]), acc[rg][c4], 0, 0, 0);
    }
  }

  const int cb = l & 15;
  const int rsub = (l >> 4) << 2;
  if constexpr (EPI == 0) {
    u16* out = (u16*)outv;
#pragma unroll
    for (int rg = 0; rg < 4; ++rg)
#pragma unroll
      for (int c4 = 0; c4 < CT4; ++c4) {
        int col = (w * CT4 + c4) * 16 + cb;
#pragma unroll
        for (int r = 0; r < 4; ++r) {
          int row = wr0 + rg * 16 + rsub + r;
          if (row < N_) out[(long)row * C + col] = f2b(acc[rg][c4][r]);
        }
      }
  } else if constexpr (EPI == 2 || EPI == 3) {
    u16* out = (u16*)outv;
#pragma unroll
    for (int rg = 0; rg < 4; ++rg)
#pragma unroll
      for (int c4 = 0; c4 < CT4; ++c4) {
        int col = (w * CT4 + c4) * 16 + cb;
        float bv = bias[col];
#pragma unroll
        for (int r = 0; r < 4; ++r) {
          int row = wr0 + rg * 16 + rsub + r;
          if (row < N_) {
            float g = gelu_f(acc[rg][c4][r] + bv);
            if constexpr (EPI == 2) g *= mulf[(long)row * C + col];
            out[(long)row * C + col] = f2b(g);
          }
        }
      }
  } else if constexpr (EPI == 4) {          // C=64: leaky + row l2norm (f32 out)
    __shared__ float ssb[64][4];
    float* out = (float*)outv;
    const int col = w * 16 + cb;
    const float bv = bias[col];
    float xv[4][4];
#pragma unroll
    for (int rg = 0; rg < 4; ++rg)
#pragma unroll
      for (int r = 0; r < 4; ++r) {
        float x = acc[rg][0][r] + bv;
        x = x > 0.f ? x : 0.01f * x;
        xv[rg][r] = x;
        float ss = x * x;
#pragma unroll
        for (int o = 1; o < 16; o <<= 1) ss += __shfl_xor(ss, o);
        if (cb == 0) ssb[rg * 16 + rsub + r][w] = ss;
      }
    __syncthreads();
#pragma unroll
    for (int rg = 0; rg < 4; ++rg)
#pragma unroll
      for (int r = 0; r < 4; ++r) {
        int lrow = rg * 16 + rsub + r;
        float ss = ssb[lrow][0] + ssb[lrow][1] + ssb[lrow][2] + ssb[lrow][3];
        float sc = 1.f / fmaxf(sqrtf(ss), 1e-12f);
        int row = wr0 + lrow;
        if (row < N_) out[(long)row * 64 + col] = xv[rg][r] * sc;
      }
  } else {                                  // EPI == 5: dual mask (C=256)
#pragma unroll
    for (int c4 = 0; c4 < CT4; ++c4) {
      const int ct = w * CT4 + c4;
      const bool lo = ct < 8;
      u16* op = lo ? (u16*)outv : (u16*)outv2;
      const int cc = (ct & 7) * 16 + cb;
      float bv = lo ? bias[cc] : bias2[cc];
#pragma unroll
      for (int rg = 0; rg < 4; ++rg)
#pragma unroll
        for (int r = 0; r < 4; ++r) {
          int row = wr0 + rg * 16 + rsub + r;
          if (row < N_) {
            float x = acc[rg][c4][r] + bv;
            float fv = b2f(mulb[(long)row * 128 + cc]);
            op[(long)row * 128 + cc] = f2b(fv * sigmoid_f(x));
          }
        }
    }
  }
}

// ================= SAGE gather (4x unrolled, split accumulators) =================
__global__ __launch_bounds__(256) void gather_bf128(const u16* __restrict__ h,
    const int* __restrict__ rowptr, const int* __restrict__ colsrc,
    u16* __restrict__ out) {
  int node = blockIdx.x * 4 + (threadIdx.x >> 6);
  int lane = threadIdx.x & 63;
  if (node >= N_) return;
  int beg = rowptr[node], end = rowptr[node + 1];
  float inv = 1.f / fmaxf((float)(end - beg), 1.f);
  float a0 = 0.f, a1 = 0.f, b0 = 0.f, b1 = 0.f;
  int j = beg;
  for (; j + 4 <= end; j += 4) {
    int s0 = colsrc[j], s1 = colsrc[j + 1], s2 = colsrc[j + 2], s3 = colsrc[j + 3];
    u32 v0 = *(const u32*)(h + (long)s0 * 128 + 2 * lane);
    u32 v1 = *(const u32*)(h + (long)s1 * 128 + 2 * lane);
    u32 v2 = *(const u32*)(h + (long)s2 * 128 + 2 * lane);
    u32 v3 = *(const u32*)(h + (long)s3 * 128 + 2 * lane);
    a0 += b2f((u16)(v0 & 0xffffu)) + b2f((u16)(v2 & 0xffffu));
    a1 += b2f((u16)(v0 >> 16))     + b2f((u16)(v2 >> 16));
    b0 += b2f((u16)(v1 & 0xffffu)) + b2f((u16)(v3 & 0xffffu));
    b1 += b2f((u16)(v1 >> 16))     + b2f((u16)(v3 >> 16));
  }
  for (; j < end; ++j) {
    int s = colsrc[j];
    u32 v = *(const u32*)(h + (long)s * 128 + 2 * lane);
    a0 += b2f((u16)(v & 0xffffu));
    a1 += b2f((u16)(v >> 16));
  }
  a0 += b0; a1 += b1;
  u32 r = (u32)f2b(a0 * inv) | ((u32)f2b(a1 * inv) << 16);
  *(u32*)(out + (long)node * 128 + 2 * lane) = r;
}

// K=64: halves process alternating edges; 4 edges per iteration
__global__ __launch_bounds__(256) void gather_bf64(const u16* __restrict__ h,
    const int* __restrict__ rowptr, const int* __restrict__ colsrc,
    u16* __restrict__ out) {
  int node = blockIdx.x * 4 + (threadIdx.x >> 6);
  int lane = threadIdx.x & 63;
  if (node >= N_) return;
  int beg = rowptr[node], end = rowptr[node + 1];
  int half = lane >> 5, cl = lane & 31;
  float a0 = 0.f, a1 = 0.f, b0 = 0.f, b1 = 0.f;
  int j = beg;
  for (; j + 4 <= end; j += 4) {
    int s0 = colsrc[j + half], s1 = colsrc[j + 2 + half];
    u32 v0 = *(const u32*)(h + (long)s0 * 64 + 2 * cl);
    u32 v1 = *(const u32*)(h + (long)s1 * 64 + 2 * cl);
    a0 += b2f((u16)(v0 & 0xffffu));
    a1 += b2f((u16)(v0 >> 16));
    b0 += b2f((u16)(v1 & 0xffffu));
    b1 += b2f((u16)(v1 >> 16));
  }
  for (; j + half < end; j += 2) {
    int s = colsrc[j + half];
    u32 v = *(const u32*)(h + (long)s * 64 + 2 * cl);
    a0 += b2f((u16)(v & 0xffffu));
    a1 += b2f((u16)(v >> 16));
  }
  a0 += b0; a1 += b1;
  a0 += __shfl_xor(a0, 32);
  a1 += __shfl_xor(a1, 32);
  if (lane < 32) {
    float inv = 1.f / fmaxf((float)(end - beg), 1.f);
    u32 r = (u32)f2b(a0 * inv) | ((u32)f2b(a1 * inv) << 16);
    *(u32*)(out + (long)node * 64 + 2 * lane) = r;
  }
}

// ================= fused GATv2 (DPP reduce, 4x unroll) =================
// split-lane layout: lane l owns cols {2l,2l+1}; lanes 0-31 = head0, 32-63 = head1.
template <bool LAYER1>
__global__ __launch_bounds__(256) void gat_fused(const u16* __restrict__ fsfd,
    const int* __restrict__ rowptr, const int* __restrict__ colsrc,
    const float* __restrict__ attn, const float* __restrict__ bias,
    const float* __restrict__ drop, void* __restrict__ outv) {
  int node = blockIdx.x * 4 + (threadIdx.x >> 6);
  int lane = threadIdx.x & 63;
  if (node >= N_) return;
  float2 av = *(const float2*)(attn + 2 * lane);
  u32 fdv = *(const u32*)(fsfd + (long)node * 256 + 128 + 2 * lane);
  float fd0 = b2f((u16)(fdv & 0xffffu)), fd1 = b2f((u16)(fdv >> 16));
  float d_own = 0.f, acc0 = 0.f, acc1 = 0.f;
  const int beg = rowptr[node], end = rowptr[node + 1];
  int j = beg;
  for (; j + 4 <= end; j += 4) {
    int s0 = colsrc[j], s1 = colsrc[j + 1], s2 = colsrc[j + 2], s3 = colsrc[j + 3];
    u32 v0 = *(const u32*)(fsfd + (long)s0 * 256 + 2 * lane);
    u32 v1 = *(const u32*)(fsfd + (long)s1 * 256 + 2 * lane);
    u32 v2 = *(const u32*)(fsfd + (long)s2 * 256 + 2 * lane);
    u32 v3 = *(const u32*)(fsfd + (long)s3 * 256 + 2 * lane);
    float f00 = b2f((u16)(v0 & 0xffffu)), f01 = b2f((u16)(v0 >> 16));
    float f10 = b2f((u16)(v1 & 0xffffu)), f11 = b2f((u16)(v1 >> 16));
    float f20 = b2f((u16)(v2 & 0xffffu)), f21 = b2f((u16)(v2 >> 16));
    float f30 = b2f((u16)(v3 & 0xffffu)), f31 = b2f((u16)(v3 >> 16));
    float x00 = f00 + fd0; x00 = fmaxf(x00, 0.2f * x00);
    float x01 = f01 + fd1; x01 = fmaxf(x01, 0.2f * x01);
    float x10 = f10 + fd0; x10 = fmaxf(x10, 0.2f * x10);
    float x11 = f11 + fd1; x11 = fmaxf(x11, 0.2f * x11);
    float x20 = f20 + fd0; x20 = fmaxf(x20, 0.2f * x20);
    float x21 = f21 + fd1; x21 = fmaxf(x21, 0.2f * x21);
    float x30 = f30 + fd0; x30 = fmaxf(x30, 0.2f * x30);
    float x31 = f31 + fd1; x31 = fmaxf(x31, 0.2f * x31);
    float c0 = half_reduce(x00 * av.x + x01 * av.y);
    float c1 = half_reduce(x10 * av.x + x11 * av.y);
    float c2 = half_reduce(x20 * av.x + x21 * av.y);
    float c3 = half_reduce(x30 * av.x + x31 * av.y);
    float e0 = __expf(c0), e1 = __expf(c1), e2 = __expf(c2), e3 = __expf(c3);
    d_own += (e0 + e1) + (e2 + e3);
    acc0 += e0 * f00 + e1 * f10 + e2 * f20 + e3 * f30;
    acc1 += e0 * f01 + e1 * f11 + e2 * f21 + e3 * f31;
  }
  for (; j < end; ++j) {
    int s = colsrc[j];
    u32 fv = *(const u32*)(fsfd + (long)s * 256 + 2 * lane);
    float f0 = b2f((u16)(fv & 0xffffu)), f1 = b2f((u16)(fv >> 16));
    float x0 = f0 + fd0; x0 = fmaxf(x0, 0.2f * x0);
    float x1 = f1 + fd1; x1 = fmaxf(x1, 0.2f * x1);
    float c = half_reduce(x0 * av.x + x1 * av.y);
    float e = __expf(c);
    d_own += e;
    acc0 += e * f0;
    acc1 += e * f1;
  }
  float2 bv = *(const float2*)(bias + 2 * lane);
  float inv = d_own > 0.f ? 1.f / d_own : 0.f;
  float g0 = gelu_f(bv.x + acc0 * inv);
  float g1 = gelu_f(bv.y + acc1 * inv);
  float v0 = 0.5f * (g0 + __shfl_xor(g0, 32));
  float v1 = 0.5f * (g1 + __shfl_xor(g1, 32));
  if constexpr (LAYER1) {
    if (lane < 32) {
      float2 dv = *(const float2*)(drop + (long)node * 64 + 2 * lane);
      u32 r = (u32)f2b(v0 * dv.x) | ((u32)f2b(v1 * dv.y) << 16);
      *(u32*)((u16*)outv + (long)node * 64 + 2 * lane) = r;
    }
  } else {
    float ss = v0 * v0 + v1 * v1;
#pragma unroll
    for (int o = 16; o; o >>= 1) ss += __shfl_xor(ss, o);
    float sc = 1.f / fmaxf(sqrtf(ss), 1e-12f);
    if (lane < 32) {
      float2 r; r.x = v0 * sc; r.y = v1 * sc;
      *(float2*)((float*)outv + (long)node * 64 + 2 * lane) = r;
    }
  }
}

extern "C" void kernel_launch(void* const* d_in, const int* in_sizes, int n_in,
                              void* d_out, int out_size, void* d_ws, size_t ws_size,
                              hipStream_t stream) {
  const float* feat = (const float*)d_in[0];
  const int*   esrc = (const int*)d_in[1];
  const int*   edst = (const int*)d_in[2];
  const float* Wmt = (const float*)d_in[3],  *bmt = (const float*)d_in[4];
  const float* Wms = (const float*)d_in[5],  *bms = (const float*)d_in[6];
  const float* W1s = (const float*)d_in[7],  *W1n = (const float*)d_in[8],  *b1 = (const float*)d_in[9];
  const float* W2s = (const float*)d_in[10], *W2n = (const float*)d_in[11], *b2 = (const float*)d_in[12];
  const float* g1Ws = (const float*)d_in[13], *g1Wd = (const float*)d_in[14];
  const float* g1a  = (const float*)d_in[15], *g1b  = (const float*)d_in[16];
  const float* g2Ws = (const float*)d_in[17], *g2Wd = (const float*)d_in[18];
  const float* g2a  = (const float*)d_in[19], *g2b  = (const float*)d_in[20];
  const float* W3  = (const float*)d_in[21], *b3 = (const float*)d_in[22];
  const float* dropt = (const float*)d_in[23], *drops = (const float*)d_in[24];

  float* out_t = (float*)d_out;
  float* out_s = out_t + (long)N_ * 64;

  // workspace (u16 units)
  u16* wsh = (u16*)d_ws;
  u16* featbf = wsh;                 // N*128
  u16* hbuf_t = wsh +  6400000;      // N*128
  u16* hbuf_s = wsh + 12800000;      // N*128
  u16* hn     = wsh + 19200000;      // N*128
  u16* h1     = wsh + 25600000;      // N*64
  u16* hn2    = wsh + 28800000;      // N*64
  u16* h2     = wsh + 32000000;      // N*64
  u16* hs1    = wsh + 35200000;      // N*64
  u16* fsfd   = wsh + 38400000;      // N*256
  u16* Wpk    = wsh + 51200000;      // 118784
  int* degi   = (int*)(wsh + 51318784);  // N
  int* cursor = degi + N_;               // N
  int* rowptr = cursor + N_;             // N+1
  int* colsrc = rowptr + N_ + 1;         // E
  int* bsum   = colsrc + E_;             // NB_
  int* bpre   = bsum + NB_;              // NB_+1

  const u16* WpMT = Wpk;             // [Wmt|Wms] fused
  const u16* WpS1 = Wpk + 32768;
  const u16* WpS2 = Wpk + 49152;
  const u16* WpG1 = Wpk + 57344;
  const u16* WpG2 = Wpk + 90112;
  const u16* WpW3 = Wpk + 106496;

  constexpr int GB = (N_ + 63) / 64;

  // ---- CSR + packing ----
  (void)hipMemsetAsync(degi, 0, (size_t)(2 * N_) * sizeof(int), stream);
  deg_int_kernel<<<(E_ + 255) / 256, 256, 0, stream>>>(edst, degi);
  scan_local<<<NB_, 256, 0, stream>>>(degi, rowptr, bsum);
  scan_block<<<1, 256, 0, stream>>>(bsum, bpre);
  scan_add<<<(N_ + 256) / 256, 256, 0, stream>>>(rowptr, bpre);
  csr_fill<<<(E_ + 255) / 256, 256, 0, stream>>>(esrc, edst, rowptr, cursor, colsrc);
  pack_feat<<<N_ * 128 / 4 / 256, 256, 0, stream>>>(feat, featbf);
  pack_w<<<464, 256, 0, stream>>>(Wmt, Wms, W1s, W1n, W2s, W2n,
                                  g1Ws, g1Wd, g2Ws, g2Wd, W3, Wpk);

  // ---- both feature masks in one GEMM ----
  gemm_mfma<128, 0, 256, 5><<<GB, 256, 0, stream>>>(featbf, nullptr, WpMT, bmt, bms,
                                                    featbf, nullptr, hbuf_t, hbuf_s);

  // ---- topology branch (SAGE) ----
  gather_bf128<<<N_ / 4, 256, 0, stream>>>(hbuf_t, rowptr, colsrc, hn);
  gemm_mfma<128, 128, 64, 2><<<GB, 256, 0, stream>>>(hbuf_t, hn, WpS1, b1, nullptr,
                                                     nullptr, dropt, h1, nullptr);
  gather_bf64<<<N_ / 4, 256, 0, stream>>>(h1, rowptr, colsrc, hn2);
  gemm_mfma<64, 64, 64, 3><<<GB, 256, 0, stream>>>(h1, hn2, WpS2, b2, nullptr,
                                                   nullptr, nullptr, h2, nullptr);
  gemm_mfma<64, 128, 64, 4><<<GB, 256, 0, stream>>>(h2, featbf, WpW3, b3, nullptr,
                                                    nullptr, nullptr, out_t, nullptr);

  // ---- semantic branch (GATv2) ----
  gemm_mfma<128, 0, 256, 0><<<GB, 256, 0, stream>>>(hbuf_s, nullptr, WpG1, nullptr, nullptr,
                                                    nullptr, nullptr, fsfd, nullptr);
  gat_fused<true><<<N_ / 4, 256, 0, stream>>>(fsfd, rowptr, colsrc, g1a, g1b, drops, hs1);
  gemm_mfma<64, 0, 256, 0><<<GB, 256, 0, stream>>>(hs1, nullptr, WpG2, nullptr, nullptr,
                                                   nullptr, nullptr, fsfd, nullptr);
  gat_fused<false><<<N_ / 4, 256, 0, stream>>>(fsfd, rowptr, colsrc, g2a, g2b, nullptr, out_s);
}

// Round 9
// 280.014 us; speedup vs baseline: 8.8321x; 1.0660x over previous
//
#include <hip/hip_runtime.h>
#include <math.h>

constexpr int N_  = 50000;
constexpr int E_  = 500000;
constexpr int NB_ = (N_ + 255) / 256;   // 196 scan blocks

typedef unsigned short u16;
typedef unsigned int u32;
typedef short short8 __attribute__((ext_vector_type(8)));
typedef __bf16 bf16x8 __attribute__((ext_vector_type(8)));
typedef float f32x4 __attribute__((ext_vector_type(4)));
typedef short short4v __attribute__((ext_vector_type(4)));

#define DINL __device__ __forceinline__

DINL float gelu_f(float x) { return 0.5f * x * (1.f + erff(x * 0.70710678118654752f)); }
DINL float sigmoid_f(float x) { return 1.f / (1.f + expf(-x)); }
DINL u16 f2b(float x) {            // f32 -> bf16 RNE
  unsigned u = __float_as_uint(x);
  return (u16)((u + 0x7FFFu + ((u >> 16) & 1u)) >> 16);
}
DINL float b2f(u16 b) { return __uint_as_float(((unsigned)b) << 16); }

// butterfly sum over each 32-lane half: 4 DPP stages (VALU pipe) + 1 ds_swizzle (xor16)
template <int CTRL>
DINL float dpp_add(float c) {
  int p = __builtin_amdgcn_update_dpp(0, __builtin_bit_cast(int, c), CTRL, 0xf, 0xf, false);
  return c + __builtin_bit_cast(float, p);
}
DINL float half_reduce(float c) {
  c = dpp_add<0xB1>(c);    // quad_perm [1,0,3,2]  : xor1
  c = dpp_add<0x4E>(c);    // quad_perm [2,3,0,1]  : xor2
  c = dpp_add<0x141>(c);   // row_half_mirror      : xor4
  c = dpp_add<0x140>(c);   // row_mirror           : xor8
  int p = __builtin_amdgcn_ds_swizzle(__builtin_bit_cast(int, c), 0x401F);  // xor16
  return c + __builtin_bit_cast(float, p);
}

// ================= CSR build =================
__global__ void deg_int_kernel(const int* __restrict__ dst, int* __restrict__ deg) {
  int t = blockIdx.x * 256 + threadIdx.x;
  if (t < E_) atomicAdd(&deg[dst[t]], 1);
}

__global__ __launch_bounds__(256) void scan_local(const int* __restrict__ deg,
    int* __restrict__ rowptr, int* __restrict__ bsum) {
  __shared__ int sums[4];
  const int tid = threadIdx.x, lane = tid & 63, wid = tid >> 6;
  const int i = blockIdx.x * 256 + tid;
  int v = (i < N_) ? deg[i] : 0;
  int x = v;
#pragma unroll
  for (int o = 1; o < 64; o <<= 1) { int y = __shfl_up(x, o); if (lane >= o) x += y; }
  if (lane == 63) sums[wid] = x;
  __syncthreads();
  int woff = 0;
#pragma unroll
  for (int w = 0; w < 3; ++w) if (w < wid) woff += sums[w];
  if (i < N_) rowptr[i] = x - v + woff;
  if (tid == 255) bsum[blockIdx.x] = woff + x;
}

__global__ __launch_bounds__(256) void scan_block(const int* __restrict__ bsum,
                                                  int* __restrict__ bpre) {
  __shared__ int sums[4];
  const int tid = threadIdx.x, lane = tid & 63, wid = tid >> 6;
  int v = (tid < NB_) ? bsum[tid] : 0;
  int x = v;
#pragma unroll
  for (int o = 1; o < 64; o <<= 1) { int y = __shfl_up(x, o); if (lane >= o) x += y; }
  if (lane == 63) sums[wid] = x;
  __syncthreads();
  int woff = 0;
#pragma unroll
  for (int w = 0; w < 3; ++w) if (w < wid) woff += sums[w];
  if (tid < NB_) bpre[tid] = x - v + woff;
  if (tid == 255) bpre[NB_] = woff + x;
}

__global__ __launch_bounds__(256) void scan_add(int* __restrict__ rowptr,
                                                const int* __restrict__ bpre) {
  int i = blockIdx.x * 256 + threadIdx.x;
  if (i < N_) rowptr[i] += bpre[i >> 8];
  else if (i == N_) rowptr[N_] = bpre[NB_];
}

__global__ void csr_fill(const int* __restrict__ src, const int* __restrict__ dst,
                         const int* __restrict__ rowptr, int* __restrict__ cursor,
                         int* __restrict__ colsrc) {
  int e = blockIdx.x * 256 + threadIdx.x;
  if (e >= E_) return;
  int d = dst[e];
  int pos = rowptr[d] + atomicAdd(&cursor[d], 1);
  colsrc[pos] = src[e];
}

// ================= packing =================
__global__ __launch_bounds__(256) void pack_feat(const float* __restrict__ f,
                                                 u16* __restrict__ o) {
  int t = blockIdx.x * 256 + threadIdx.x;
  float4 v = ((const float4*)f)[t];
  short4v r;
  r[0] = (short)f2b(v.x); r[1] = (short)f2b(v.y);
  r[2] = (short)f2b(v.z); r[3] = (short)f2b(v.w);
  ((short4v*)o)[t] = r;
}

// pack weights into MFMA fragment order (identical for A- and B-operand use):
// dst[((ct*(K/32)+ks)*64+lane)*8+j] = W[ks*32+(lane>>4)*8+j][ct*16+(lane&15)]
__global__ __launch_bounds__(256) void pack_w(
    const float* __restrict__ Wmt, const float* __restrict__ Wms,
    const float* __restrict__ W1s, const float* __restrict__ W1n,
    const float* __restrict__ W2s, const float* __restrict__ W2n,
    const float* __restrict__ g1Ws, const float* __restrict__ g1Wd,
    const float* __restrict__ g2Ws, const float* __restrict__ g2Wd,
    const float* __restrict__ W3, u16* __restrict__ dst) {
  int e = blockIdx.x * 256 + threadIdx.x;
  const float *Wa, *Wb = nullptr;
  int K1, K2 = 0, Ca, Cb = 0, st;
  if (e < 16384)       { Wa = Wmt;  K1 = 128; Ca = 128;           st = 0; }
  else if (e < 32768)  { Wa = Wms;  K1 = 128; Ca = 128;           st = 16384; }
  else if (e < 49152)  { Wa = W1s;  Wb = W1n; K1 = 128; K2 = 128; Ca = 64;  st = 32768; }
  else if (e < 57344)  { Wa = W2s;  Wb = W2n; K1 = 64;  K2 = 64;  Ca = 64;  st = 49152; }
  else if (e < 90112)  { Wa = g1Ws; Wb = g1Wd; K1 = 128; Ca = 128; Cb = 128; st = 57344; }
  else if (e < 106496) { Wa = g2Ws; Wb = g2Wd; K1 = 64;  Ca = 128; Cb = 128; st = 90112; }
  else                 { Wa = W3;   K1 = 192; Ca = 64;            st = 106496; }
  int el = e - st;
  int Kt = K1 + K2;
  int ct = el / (Kt * 16);
  int rem = el - ct * Kt * 16;
  int ks = rem >> 9, rem2 = rem & 511, lane = rem2 >> 3, j = rem2 & 7;
  int k = ks * 32 + ((lane >> 4) << 3) + j;
  int c = ct * 16 + (lane & 15);
  float v;
  if (k < K1) v = (c < Ca) ? Wa[k * Ca + c] : Wb[k * Cb + (c - Ca)];
  else        v = Wb[(k - K1) * Ca + c];
  dst[e] = f2b(v);
}

// ================= MFMA GEMM =================
// Swapped operands: W-frag is the MFMA A-operand, activation-frag is B.
// D comes out transposed: lane l holds node (l&15) of each 16-row group,
// output cols (l>>4)*4 + r -> contiguous short4/float4 stores.
// LDS is XOR-swizzled: 16B-chunk index ^= (row & 7)  -> conflict-free ds_read_b128.
// EPI: 0 plain bf16, 2 gelu*drop, 3 gelu, 4 leaky+l2norm(f32),
//      5 dual-mask (C=256): col tiles 0-7 -> outv, 8-15 -> outv2; mask read from LDS
template <int K1, int K2, int C, int EPI>
__global__ __launch_bounds__(256) void gemm_mfma(
    const u16* __restrict__ A1, const u16* __restrict__ A2,
    const u16* __restrict__ Wp, const float* __restrict__ bias,
    const float* __restrict__ bias2, const float* __restrict__ mulf,
    void* __restrict__ outv, void* __restrict__ outv2) {
  constexpr int K = K1 + K2, KS = K / 32, CT4 = C / 64;
  constexpr int NCH1 = K1 / 8, NCH2 = K2 / 8;
  __shared__ u16 alds[64 * K];
  const int tid = threadIdx.x;
  const int w = tid >> 6, l = tid & 63;
  const int wr0 = blockIdx.x * 64;

  // preload W fragments for this wave's column quadrant
  short8 wfrag[KS][CT4];
#pragma unroll
  for (int ks = 0; ks < KS; ++ks)
#pragma unroll
    for (int c4 = 0; c4 < CT4; ++c4)
      wfrag[ks][c4] = *(const short8*)(Wp +
          ((size_t)((w * CT4 + c4) * KS + ks) * 64 + l) * 8);

  // stage activations into LDS, swizzled
  for (int i = tid; i < 64 * NCH1; i += 256) {
    int rr = i / NCH1, kc = i % NCH1;
    int gr = wr0 + rr; if (gr >= N_) gr = N_ - 1;
    short8 v = *(const short8*)(A1 + (long)gr * K1 + kc * 8);
    *(short8*)&alds[rr * K + ((kc ^ (rr & 7)) << 3)] = v;
  }
  if constexpr (K2 > 0) {
    for (int i = tid; i < 64 * NCH2; i += 256) {
      int rr = i / NCH2, kc = i % NCH2;
      int gr = wr0 + rr; if (gr >= N_) gr = N_ - 1;
      short8 v = *(const short8*)(A2 + (long)gr * K2 + kc * 8);
      *(short8*)&alds[rr * K + (((NCH1 + kc) ^ (rr & 7)) << 3)] = v;
    }
  }
  __syncthreads();

  f32x4 acc[4][CT4];
#pragma unroll
  for (int rg = 0; rg < 4; ++rg)
#pragma unroll
    for (int c4 = 0; c4 < CT4; ++c4) acc[rg][c4] = (f32x4){0.f, 0.f, 0.f, 0.f};

#pragma unroll
  for (int ks = 0; ks < KS; ++ks) {
#pragma unroll
    for (int rg = 0; rg < 4; ++rg) {
      const int nr = rg * 16 + (l & 15);
      const int ch = (ks * 4 + (l >> 4)) ^ (nr & 7);
      short8 av = *(const short8*)&alds[nr * K + (ch << 3)];
      bf16x8 bf = __builtin_bit_cast(bf16x8, av);
#pragma unroll
      for (int c4 = 0; c4 < CT4; ++c4)
        acc[rg][c4] = __builtin_amdgcn_mfma_f32_16x16x32_bf16(
            __builtin_bit_cast(bf16x8, wfrag[ks][c4]), bf, acc[rg][c4], 0, 0, 0);
    }
  }

  const int colq = (l >> 4) << 2;            // col offset within 16-col tile
  if constexpr (EPI == 0) {
    u16* out = (u16*)outv;
#pragma unroll
    for (int rg = 0; rg < 4; ++rg) {
      int row = wr0 + rg * 16 + (l & 15);
      if (row >= N_) continue;
#pragma unroll
      for (int c4 = 0; c4 < CT4; ++c4) {
        int colb = (w * CT4 + c4) * 16 + colq;
        short4v s;
#pragma unroll
        for (int r = 0; r < 4; ++r) s[r] = (short)f2b(acc[rg][c4][r]);
        *(short4v*)(out + (long)row * C + colb) = s;
      }
    }
  } else if constexpr (EPI == 2 || EPI == 3) {
    u16* out = (u16*)outv;
    const int colb = w * 16 + colq;          // CT4 == 1
    float4 bv = *(const float4*)(bias + colb);
#pragma unroll
    for (int rg = 0; rg < 4; ++rg) {
      int row = wr0 + rg * 16 + (l & 15);
      if (row >= N_) continue;
      float4 dv;
      if constexpr (EPI == 2) dv = *(const float4*)(mulf + (long)row * C + colb);
      short4v s;
#pragma unroll
      for (int r = 0; r < 4; ++r) {
        float g = gelu_f(acc[rg][0][r] + ((const float*)&bv)[r]);
        if constexpr (EPI == 2) g *= ((const float*)&dv)[r];
        s[r] = (short)f2b(g);
      }
      *(short4v*)(out + (long)row * C + colb) = s;
    }
  } else if constexpr (EPI == 4) {          // C=64: leaky + row l2norm (f32 out)
    __shared__ float ssb[64][4];
    float* out = (float*)outv;
    const int colb = w * 16 + colq;
    float4 bv = *(const float4*)(bias + colb);
    float xv[4][4];
#pragma unroll
    for (int rg = 0; rg < 4; ++rg) {
      float ss = 0.f;
#pragma unroll
      for (int r = 0; r < 4; ++r) {
        float x = acc[rg][0][r] + ((const float*)&bv)[r];
        x = fmaxf(x, 0.01f * x);
        xv[rg][r] = x; ss += x * x;
      }
      ss += __shfl_xor(ss, 16);
      ss += __shfl_xor(ss, 32);
      if (l < 16) ssb[rg * 16 + l][w] = ss;
    }
    __syncthreads();
#pragma unroll
    for (int rg = 0; rg < 4; ++rg) {
      int nl = rg * 16 + (l & 15);
      int row = wr0 + nl;
      if (row >= N_) continue;
      float ss = ssb[nl][0] + ssb[nl][1] + ssb[nl][2] + ssb[nl][3];
      float sc = 1.f / fmaxf(sqrtf(ss), 1e-12f);
      float4 o;
#pragma unroll
      for (int r = 0; r < 4; ++r) ((float*)&o)[r] = xv[rg][r] * sc;
      *(float4*)(out + (long)row * 64 + colb) = o;
    }
  } else {                                  // EPI == 5: dual mask (C=256, K=128)
#pragma unroll
    for (int c4 = 0; c4 < CT4; ++c4) {
      const int ct = w * CT4 + c4;
      const bool lo = ct < 8;
      u16* op = lo ? (u16*)outv : (u16*)outv2;
      const int ccb = (ct & 7) * 16 + colq;
      float4 bv = *(const float4*)((lo ? bias : bias2) + ccb);
#pragma unroll
      for (int rg = 0; rg < 4; ++rg) {
        int nl = rg * 16 + (l & 15);
        int row = wr0 + nl;
        if (row >= N_) continue;
        // feat values from (swizzled) LDS — same row, cols ccb..ccb+3
        int ch = (ccb >> 3) ^ (nl & 7);
        short4v fq = *(const short4v*)&alds[nl * K + (ch << 3) + (ccb & 7)];
        short4v s;
#pragma unroll
        for (int r = 0; r < 4; ++r) {
          float x = acc[rg][c4][r] + ((const float*)&bv)[r];
          float fv = b2f((u16)fq[r]);
          s[r] = (short)f2b(fv * sigmoid_f(x));
        }
        *(short4v*)(op + (long)row * 128 + ccb) = s;
      }
    }
  }
}

// ================= SAGE gather (4x unrolled, split accumulators) =================
__global__ __launch_bounds__(256) void gather_bf128(const u16* __restrict__ h,
    const int* __restrict__ rowptr, const int* __restrict__ colsrc,
    u16* __restrict__ out) {
  int node = blockIdx.x * 4 + (threadIdx.x >> 6);
  int lane = threadIdx.x & 63;
  if (node >= N_) return;
  int beg = rowptr[node], end = rowptr[node + 1];
  float inv = 1.f / fmaxf((float)(end - beg), 1.f);
  float a0 = 0.f, a1 = 0.f, b0 = 0.f, b1 = 0.f;
  int j = beg;
  for (; j + 4 <= end; j += 4) {
    int s0 = colsrc[j], s1 = colsrc[j + 1], s2 = colsrc[j + 2], s3 = colsrc[j + 3];
    u32 v0 = *(const u32*)(h + (long)s0 * 128 + 2 * lane);
    u32 v1 = *(const u32*)(h + (long)s1 * 128 + 2 * lane);
    u32 v2 = *(const u32*)(h + (long)s2 * 128 + 2 * lane);
    u32 v3 = *(const u32*)(h + (long)s3 * 128 + 2 * lane);
    a0 += b2f((u16)(v0 & 0xffffu)) + b2f((u16)(v2 & 0xffffu));
    a1 += b2f((u16)(v0 >> 16))     + b2f((u16)(v2 >> 16));
    b0 += b2f((u16)(v1 & 0xffffu)) + b2f((u16)(v3 & 0xffffu));
    b1 += b2f((u16)(v1 >> 16))     + b2f((u16)(v3 >> 16));
  }
  for (; j < end; ++j) {
    int s = colsrc[j];
    u32 v = *(const u32*)(h + (long)s * 128 + 2 * lane);
    a0 += b2f((u16)(v & 0xffffu));
    a1 += b2f((u16)(v >> 16));
  }
  a0 += b0; a1 += b1;
  u32 r = (u32)f2b(a0 * inv) | ((u32)f2b(a1 * inv) << 16);
  *(u32*)(out + (long)node * 128 + 2 * lane) = r;
}

// K=64: halves process alternating edges; 4 edges per iteration
__global__ __launch_bounds__(256) void gather_bf64(const u16* __restrict__ h,
    const int* __restrict__ rowptr, const int* __restrict__ colsrc,
    u16* __restrict__ out) {
  int node = blockIdx.x * 4 + (threadIdx.x >> 6);
  int lane = threadIdx.x & 63;
  if (node >= N_) return;
  int beg = rowptr[node], end = rowptr[node + 1];
  int half = lane >> 5, cl = lane & 31;
  float a0 = 0.f, a1 = 0.f, b0 = 0.f, b1 = 0.f;
  int j = beg;
  for (; j + 4 <= end; j += 4) {
    int s0 = colsrc[j + half], s1 = colsrc[j + 2 + half];
    u32 v0 = *(const u32*)(h + (long)s0 * 64 + 2 * cl);
    u32 v1 = *(const u32*)(h + (long)s1 * 64 + 2 * cl);
    a0 += b2f((u16)(v0 & 0xffffu));
    a1 += b2f((u16)(v0 >> 16));
    b0 += b2f((u16)(v1 & 0xffffu));
    b1 += b2f((u16)(v1 >> 16));
  }
  for (; j + half < end; j += 2) {
    int s = colsrc[j + half];
    u32 v = *(const u32*)(h + (long)s * 64 + 2 * cl);
    a0 += b2f((u16)(v & 0xffffu));
    a1 += b2f((u16)(v >> 16));
  }
  a0 += b0; a1 += b1;
  a0 += __shfl_xor(a0, 32);
  a1 += __shfl_xor(a1, 32);
  if (lane < 32) {
    float inv = 1.f / fmaxf((float)(end - beg), 1.f);
    u32 r = (u32)f2b(a0 * inv) | ((u32)f2b(a1 * inv) << 16);
    *(u32*)(out + (long)node * 64 + 2 * lane) = r;
  }
}

// ================= fused GATv2 (DPP reduce, 4x unroll) =================
template <bool LAYER1>
__global__ __launch_bounds__(256) void gat_fused(const u16* __restrict__ fsfd,
    const int* __restrict__ rowptr, const int* __restrict__ colsrc,
    const float* __restrict__ attn, const float* __restrict__ bias,
    const float* __restrict__ drop, void* __restrict__ outv) {
  int node = blockIdx.x * 4 + (threadIdx.x >> 6);
  int lane = threadIdx.x & 63;
  if (node >= N_) return;
  float2 av = *(const float2*)(attn + 2 * lane);
  u32 fdv = *(const u32*)(fsfd + (long)node * 256 + 128 + 2 * lane);
  float fd0 = b2f((u16)(fdv & 0xffffu)), fd1 = b2f((u16)(fdv >> 16));
  float d_own = 0.f, acc0 = 0.f, acc1 = 0.f;
  const int beg = rowptr[node], end = rowptr[node + 1];
  int j = beg;
  for (; j + 4 <= end; j += 4) {
    int s0 = colsrc[j], s1 = colsrc[j + 1], s2 = colsrc[j + 2], s3 = colsrc[j + 3];
    u32 v0 = *(const u32*)(fsfd + (long)s0 * 256 + 2 * lane);
    u32 v1 = *(const u32*)(fsfd + (long)s1 * 256 + 2 * lane);
    u32 v2 = *(const u32*)(fsfd + (long)s2 * 256 + 2 * lane);
    u32 v3 = *(const u32*)(fsfd + (long)s3 * 256 + 2 * lane);
    float f00 = b2f((u16)(v0 & 0xffffu)), f01 = b2f((u16)(v0 >> 16));
    float f10 = b2f((u16)(v1 & 0xffffu)), f11 = b2f((u16)(v1 >> 16));
    float f20 = b2f((u16)(v2 & 0xffffu)), f21 = b2f((u16)(v2 >> 16));
    float f30 = b2f((u16)(v3 & 0xffffu)), f31 = b2f((u16)(v3 >> 16));
    float x00 = f00 + fd0; x00 = fmaxf(x00, 0.2f * x00);
    float x01 = f01 + fd1; x01 = fmaxf(x01, 0.2f * x01);
    float x10 = f10 + fd0; x10 = fmaxf(x10, 0.2f * x10);
    float x11 = f11 + fd1; x11 = fmaxf(x11, 0.2f * x11);
    float x20 = f20 + fd0; x20 = fmaxf(x20, 0.2f * x20);
    float x21 = f21 + fd1; x21 = fmaxf(x21, 0.2f * x21);
    float x30 = f30 + fd0; x30 = fmaxf(x30, 0.2f * x30);
    float x31 = f31 + fd1; x31 = fmaxf(x31, 0.2f * x31);
    float c0 = half_reduce(x00 * av.x + x01 * av.y);
    float c1 = half_reduce(x10 * av.x + x11 * av.y);
    float c2 = half_reduce(x20 * av.x + x21 * av.y);
    float c3 = half_reduce(x30 * av.x + x31 * av.y);
    float e0 = __expf(c0), e1 = __expf(c1), e2 = __expf(c2), e3 = __expf(c3);
    d_own += (e0 + e1) + (e2 + e3);
    acc0 += e0 * f00 + e1 * f10 + e2 * f20 + e3 * f30;
    acc1 += e0 * f01 + e1 * f11 + e2 * f21 + e3 * f31;
  }
  for (; j < end; ++j) {
    int s = colsrc[j];
    u32 fv = *(const u32*)(fsfd + (long)s * 256 + 2 * lane);
    float f0 = b2f((u16)(fv & 0xffffu)), f1 = b2f((u16)(fv >> 16));
    float x0 = f0 + fd0; x0 = fmaxf(x0, 0.2f * x0);
    float x1 = f1 + fd1; x1 = fmaxf(x1, 0.2f * x1);
    float c = half_reduce(x0 * av.x + x1 * av.y);
    float e = __expf(c);
    d_own += e;
    acc0 += e * f0;
    acc1 += e * f1;
  }
  float2 bv = *(const float2*)(bias + 2 * lane);
  float inv = d_own > 0.f ? 1.f / d_own : 0.f;
  float g0 = gelu_f(bv.x + acc0 * inv);
  float g1 = gelu_f(bv.y + acc1 * inv);
  float v0 = 0.5f * (g0 + __shfl_xor(g0, 32));
  float v1 = 0.5f * (g1 + __shfl_xor(g1, 32));
  if constexpr (LAYER1) {
    if (lane < 32) {
      float2 dv = *(const float2*)(drop + (long)node * 64 + 2 * lane);
      u32 r = (u32)f2b(v0 * dv.x) | ((u32)f2b(v1 * dv.y) << 16);
      *(u32*)((u16*)outv + (long)node * 64 + 2 * lane) = r;
    }
  } else {
    float ss = v0 * v0 + v1 * v1;
#pragma unroll
    for (int o = 16; o; o >>= 1) ss += __shfl_xor(ss, o);
    float sc = 1.f / fmaxf(sqrtf(ss), 1e-12f);
    if (lane < 32) {
      float2 r; r.x = v0 * sc; r.y = v1 * sc;
      *(float2*)((float*)outv + (long)node * 64 + 2 * lane) = r;
    }
  }
}

extern "C" void kernel_launch(void* const* d_in, const int* in_sizes, int n_in,
                              void* d_out, int out_size, void* d_ws, size_t ws_size,
                              hipStream_t stream) {
  const float* feat = (const float*)d_in[0];
  const int*   esrc = (const int*)d_in[1];
  const int*   edst = (const int*)d_in[2];
  const float* Wmt = (const float*)d_in[3],  *bmt = (const float*)d_in[4];
  const float* Wms = (const float*)d_in[5],  *bms = (const float*)d_in[6];
  const float* W1s = (const float*)d_in[7],  *W1n = (const float*)d_in[8],  *b1 = (const float*)d_in[9];
  const float* W2s = (const float*)d_in[10], *W2n = (const float*)d_in[11], *b2 = (const float*)d_in[12];
  const float* g1Ws = (const float*)d_in[13], *g1Wd = (const float*)d_in[14];
  const float* g1a  = (const float*)d_in[15], *g1b  = (const float*)d_in[16];
  const float* g2Ws = (const float*)d_in[17], *g2Wd = (const float*)d_in[18];
  const float* g2a  = (const float*)d_in[19], *g2b  = (const float*)d_in[20];
  const float* W3  = (const float*)d_in[21], *b3 = (const float*)d_in[22];
  const float* dropt = (const float*)d_in[23], *drops = (const float*)d_in[24];

  float* out_t = (float*)d_out;
  float* out_s = out_t + (long)N_ * 64;

  // workspace (u16 units)
  u16* wsh = (u16*)d_ws;
  u16* featbf = wsh;                 // N*128
  u16* hbuf_t = wsh +  6400000;      // N*128
  u16* hbuf_s = wsh + 12800000;      // N*128
  u16* hn     = wsh + 19200000;      // N*128
  u16* h1     = wsh + 25600000;      // N*64
  u16* hn2    = wsh + 28800000;      // N*64
  u16* h2     = wsh + 32000000;      // N*64
  u16* hs1    = wsh + 35200000;      // N*64
  u16* fsfd   = wsh + 38400000;      // N*256
  u16* Wpk    = wsh + 51200000;      // 118784
  int* degi   = (int*)(wsh + 51318784);  // N
  int* cursor = degi + N_;               // N
  int* rowptr = cursor + N_;             // N+1
  int* colsrc = rowptr + N_ + 1;         // E
  int* bsum   = colsrc + E_;             // NB_
  int* bpre   = bsum + NB_;              // NB_+1

  const u16* WpMT = Wpk;             // [Wmt|Wms] fused
  const u16* WpS1 = Wpk + 32768;
  const u16* WpS2 = Wpk + 49152;
  const u16* WpG1 = Wpk + 57344;
  const u16* WpG2 = Wpk + 90112;
  const u16* WpW3 = Wpk + 106496;

  constexpr int GB = (N_ + 63) / 64;

  // ---- CSR + packing ----
  (void)hipMemsetAsync(degi, 0, (size_t)(2 * N_) * sizeof(int), stream);
  deg_int_kernel<<<(E_ + 255) / 256, 256, 0, stream>>>(edst, degi);
  scan_local<<<NB_, 256, 0, stream>>>(degi, rowptr, bsum);
  scan_block<<<1, 256, 0, stream>>>(bsum, bpre);
  scan_add<<<(N_ + 256) / 256, 256, 0, stream>>>(rowptr, bpre);
  csr_fill<<<(E_ + 255) / 256, 256, 0, stream>>>(esrc, edst, rowptr, cursor, colsrc);
  pack_feat<<<N_ * 128 / 4 / 256, 256, 0, stream>>>(feat, featbf);
  pack_w<<<464, 256, 0, stream>>>(Wmt, Wms, W1s, W1n, W2s, W2n,
                                  g1Ws, g1Wd, g2Ws, g2Wd, W3, Wpk);

  // ---- both feature masks in one GEMM ----
  gemm_mfma<128, 0, 256, 5><<<GB, 256, 0, stream>>>(featbf, nullptr, WpMT, bmt, bms,
                                                    nullptr, hbuf_t, hbuf_s);

  // ---- topology branch (SAGE) ----
  gather_bf128<<<N_ / 4, 256, 0, stream>>>(hbuf_t, rowptr, colsrc, hn);
  gemm_mfma<128, 128, 64, 2><<<GB, 256, 0, stream>>>(hbuf_t, hn, WpS1, b1, nullptr,
                                                     dropt, h1, nullptr);
  gather_bf64<<<N_ / 4, 256, 0, stream>>>(h1, rowptr, colsrc, hn2);
  gemm_mfma<64, 64, 64, 3><<<GB, 256, 0, stream>>>(h1, hn2, WpS2, b2, nullptr,
                                                   nullptr, h2, nullptr);
  gemm_mfma<64, 128, 64, 4><<<GB, 256, 0, stream>>>(h2, featbf, WpW3, b3, nullptr,
                                                    nullptr, out_t, nullptr);

  // ---- semantic branch (GATv2) ----
  gemm_mfma<128, 0, 256, 0><<<GB, 256, 0, stream>>>(hbuf_s, nullptr, WpG1, nullptr, nullptr,
                                                    nullptr, fsfd, nullptr);
  gat_fused<true><<<N_ / 4, 256, 0, stream>>>(fsfd, rowptr, colsrc, g1a, g1b, drops, hs1);
  gemm_mfma<64, 0, 256, 0><<<GB, 256, 0, stream>>>(hs1, nullptr, WpG2, nullptr, nullptr,
                                                   nullptr, fsfd, nullptr);
  gat_fused<false><<<N_ / 4, 256, 0, stream>>>(fsfd, rowptr, colsrc, g2a, g2b, nullptr, out_s);
}